// Round 7
// baseline (26245.288 us; speedup 1.0000x reference)
//
#include <hip/hip_runtime.h>
#include <hip/hip_bf16.h>
#include <math.h>

#define CD 128
#define HH 4
#define DH 32
#define LL 2

using bf16 = __hip_bfloat16;

__device__ __forceinline__ float bfbits2f(unsigned int s) {
  return __uint_as_float(s << 16);
}

__device__ __forceinline__ float gelu_f(float x) {
  return 0.5f * x * (1.0f + erff(x * 0.70710678118654752f));
}

// ---- detect input formats: flags[0]=floats-are-f32, flags[1]=edge-index-is-i64 ----
__global__ void k_detect(const void* __restrict__ x, const int* __restrict__ ei,
                         int* __restrict__ flags) {
  __shared__ int cnt_f32, cnt_i32;
  if (threadIdx.x == 0) { cnt_f32 = 0; cnt_i32 = 0; }
  __syncthreads();
  int t = threadIdx.x;  // 128 threads
  unsigned short u = ((const unsigned short*)x)[2 * t];
  float v = bfbits2f((unsigned int)u);
  float av = fabsf(v);
  if (av != 0.f && (av > 1e8f || av < 1e-8f)) atomicAdd(&cnt_f32, 1);
  if (t < 64) {
    if (((const int*)ei)[2 * t + 1] != 0) atomicAdd(&cnt_i32, 1);
  }
  __syncthreads();
  if (threadIdx.x == 0) {
    flags[0] = (cnt_f32 > 8) ? 1 : 0;
    flags[1] = (cnt_i32 == 0) ? 1 : 0;
  }
}

// ---- normalize a float input (bf16 or f32) to f32 ----
__global__ void k_cvt(const void* __restrict__ in, float* __restrict__ out, int n,
                      const int* __restrict__ flags) {
  int i = blockIdx.x * blockDim.x + threadIdx.x;
  if (i >= n) return;
  if (flags[0]) out[i] = ((const float*)in)[i];
  else out[i] = bfbits2f((unsigned int)((const unsigned short*)in)[i]);
}

// ---- all parameter tensors -> contiguous f32 block, one launch ----
#define NSEG 14
struct SegTab {
  const void* src[NSEG];
  int off[NSEG];
  int total;
};
__global__ void k_cvt_params(SegTab tab, float* __restrict__ dst,
                             const int* __restrict__ flags) {
  int i = blockIdx.x * 256 + threadIdx.x;
  if (i >= tab.total) return;
  int seg = 0;
#pragma unroll
  for (int k = 1; k < NSEG; k++)
    if (i >= tab.off[k]) seg = k;
  int j = i - tab.off[seg];
  const void* src = tab.src[seg];
  dst[i] = flags[0] ? ((const float*)src)[j]
                    : bfbits2f((unsigned int)((const unsigned short*)src)[j]);
}

__device__ __forceinline__ int edge_idx(const int* __restrict__ ei, long pos, int is64) {
  return is64 ? ei[2 * pos] : ei[pos];
}

// ---- fold relation transforms into K/V weights+biases, both layers, one launch ----
__global__ void k_eff(const float* __restrict__ Wk, const float* __restrict__ bk,
                      const float* __restrict__ Wv, const float* __restrict__ bv,
                      const float* __restrict__ ar, const float* __restrict__ mr,
                      float* __restrict__ wke, float* __restrict__ bke,
                      float* __restrict__ wve, float* __restrict__ bve) {
  int c = blockIdx.x, h = blockIdx.y, z = blockIdx.z;
  int l = z >> 1, which = z & 1;
  int e = threadIdx.x;
  const float* W = (which ? Wv : Wk) + (size_t)l * CD * CD;
  const float* B = (which ? bv : bk) + (size_t)l * CD;
  const float* R = (which ? mr : ar) + (size_t)l * HH * DH * DH + h * DH * DH;
  float* Wo = (which ? wve : wke) + (size_t)l * CD * CD;
  float* Bo = (which ? bve : bke) + (size_t)l * CD;
  float acc = 0.f;
  if (c < CD) {
#pragma unroll
    for (int d = 0; d < DH; d++) acc += W[c * CD + h * DH + d] * R[d * DH + e];
    Wo[c * CD + h * DH + e] = acc;
  } else {
#pragma unroll
    for (int d = 0; d < DH; d++) acc += B[h * DH + d] * R[d * DH + e];
    Bo[h * DH + e] = acc;
  }
}

// ==== tiled GEMM v2: y[N,128] = (GELU?)(x) @ W + b, optional gated residual.
// 128x128 tile, BK=16, 16KB LDS, 8x8 micro-tile as 2x2 blocks of 4x4.
// NO min-occupancy clause (round-6 spill bug); conflict-free LDS maps. ====
template <bool GELU, bool GATE>
__global__ __launch_bounds__(256) void k_gemm_t(
    const float* __restrict__ xin, const float* __restrict__ win,
    const float* __restrict__ bin, float* __restrict__ y,
    const float* __restrict__ skip, int nrows) {
  __shared__ float xs[16][128];  // [k][row]
  __shared__ float ws[16][128];  // [k][col]
  const int t = threadIdx.x;
  const int r0 = blockIdx.x * 128;
  const int mr = (t >> 4) * 4;   // micro rows: mr..mr+3, mr+64..mr+67
  const int mc = (t & 15) * 4;   // micro cols: mc..mc+3, mc+64..mc+67
  // x staging: row t>>1 (0..127), k-octet (t&1)*8
  const int xr_ = t >> 1;
  const int xk_ = (t & 1) * 8;
  // w staging: k rows t>>5 (+8), col quad (t&31)*4
  const int wk_ = t >> 5;
  const int wc_ = (t & 31) * 4;

  const int gxr = r0 + xr_;
  const bool xok = (gxr < nrows);
  const float* xrow = xin + (size_t)gxr * CD;

  float4 xA, xB, wA, wB;
  xA = xB = make_float4(0.f, 0.f, 0.f, 0.f);
  if (xok) {
    xA = *(const float4*)(xrow + xk_);
    xB = *(const float4*)(xrow + xk_ + 4);
  }
  if (GELU) {
    xA.x = gelu_f(xA.x); xA.y = gelu_f(xA.y); xA.z = gelu_f(xA.z); xA.w = gelu_f(xA.w);
    xB.x = gelu_f(xB.x); xB.y = gelu_f(xB.y); xB.z = gelu_f(xB.z); xB.w = gelu_f(xB.w);
  }
  wA = *(const float4*)(win + (size_t)wk_ * CD + wc_);
  wB = *(const float4*)(win + (size_t)(wk_ + 8) * CD + wc_);

  float acc[8][8];
  {
    float4 b0 = *(const float4*)(bin + mc);
    float4 b1 = *(const float4*)(bin + mc + 64);
#pragma unroll
    for (int r = 0; r < 8; r++) {
      acc[r][0] = b0.x; acc[r][1] = b0.y; acc[r][2] = b0.z; acc[r][3] = b0.w;
      acc[r][4] = b1.x; acc[r][5] = b1.y; acc[r][6] = b1.z; acc[r][7] = b1.w;
    }
  }

#pragma unroll
  for (int c = 0; c < 8; c++) {
    // store staged chunk (xs scalar stores: 2 lanes/bank = free; ws float4 contiguous)
    xs[xk_ + 0][xr_] = xA.x; xs[xk_ + 1][xr_] = xA.y;
    xs[xk_ + 2][xr_] = xA.z; xs[xk_ + 3][xr_] = xA.w;
    xs[xk_ + 4][xr_] = xB.x; xs[xk_ + 5][xr_] = xB.y;
    xs[xk_ + 6][xr_] = xB.z; xs[xk_ + 7][xr_] = xB.w;
    *(float4*)&ws[wk_][wc_] = wA;
    *(float4*)&ws[wk_ + 8][wc_] = wB;
    __syncthreads();
    if (c < 7) {  // prefetch next chunk; overlaps compute below
      int k0 = (c + 1) * 16;
      xA = xB = make_float4(0.f, 0.f, 0.f, 0.f);
      if (xok) {
        xA = *(const float4*)(xrow + k0 + xk_);
        xB = *(const float4*)(xrow + k0 + xk_ + 4);
      }
      if (GELU) {
        xA.x = gelu_f(xA.x); xA.y = gelu_f(xA.y); xA.z = gelu_f(xA.z); xA.w = gelu_f(xA.w);
        xB.x = gelu_f(xB.x); xB.y = gelu_f(xB.y); xB.z = gelu_f(xB.z); xB.w = gelu_f(xB.w);
      }
      wA = *(const float4*)(win + (size_t)(k0 + wk_) * CD + wc_);
      wB = *(const float4*)(win + (size_t)(k0 + wk_ + 8) * CD + wc_);
    }
#pragma unroll
    for (int kk = 0; kk < 16; kk++) {
      float4 x0 = *(const float4*)&xs[kk][mr];
      float4 x1 = *(const float4*)&xs[kk][mr + 64];
      float4 w0 = *(const float4*)&ws[kk][mc];
      float4 w1 = *(const float4*)&ws[kk][mc + 64];
      float xr[8] = {x0.x, x0.y, x0.z, x0.w, x1.x, x1.y, x1.z, x1.w};
      float wc8[8] = {w0.x, w0.y, w0.z, w0.w, w1.x, w1.y, w1.z, w1.w};
#pragma unroll
      for (int r = 0; r < 8; r++)
#pragma unroll
        for (int cc = 0; cc < 8; cc++) acc[r][cc] += xr[r] * wc8[cc];
    }
    if (c < 7) __syncthreads();
  }

  float gg = 0.f;
  if (GATE) gg = 1.f / (1.f + __expf(-skip[0]));
#pragma unroll
  for (int r = 0; r < 8; r++) {
    int gr = r0 + mr + ((r < 4) ? r : 64 + r - 4);
    if (gr >= nrows) continue;
    float* yp = y + (size_t)gr * CD;
    float4 o0 = make_float4(acc[r][0], acc[r][1], acc[r][2], acc[r][3]);
    float4 o1 = make_float4(acc[r][4], acc[r][5], acc[r][6], acc[r][7]);
    if (GATE) {
      float4 h0 = *(const float4*)(yp + mc);
      float4 h1 = *(const float4*)(yp + mc + 64);
      o0.x = gg * o0.x + (1.f - gg) * h0.x;
      o0.y = gg * o0.y + (1.f - gg) * h0.y;
      o0.z = gg * o0.z + (1.f - gg) * h0.z;
      o0.w = gg * o0.w + (1.f - gg) * h0.w;
      o1.x = gg * o1.x + (1.f - gg) * h1.x;
      o1.y = gg * o1.y + (1.f - gg) * h1.y;
      o1.z = gg * o1.z + (1.f - gg) * h1.z;
      o1.w = gg * o1.w + (1.f - gg) * h1.w;
    }
    *(float4*)(yp + mc) = o0;
    *(float4*)(yp + mc + 64) = o1;
  }
}

// ==== CSR build ====
__global__ void k_hist(const int* __restrict__ ei, int* __restrict__ deg,
                       const int* __restrict__ flags, int E, int Nn) {
  int i = blockIdx.x * blockDim.x + threadIdx.x;
  if (i >= E) return;
  int d = edge_idx(ei, (long)E + i, flags[1]);
  if ((unsigned)d >= (unsigned)Nn) d = 0;
  atomicAdd(&deg[d], 1);
}

__global__ void k_scan1(const int* __restrict__ deg, int* __restrict__ tmp,
                        int* __restrict__ bsum, int n) {
  __shared__ int sh[256];
  int i = blockIdx.x * 256 + threadIdx.x;
  int v = (i < n) ? deg[i] : 0;
  sh[threadIdx.x] = v;
  __syncthreads();
  for (int off = 1; off < 256; off <<= 1) {
    int t = (threadIdx.x >= off) ? sh[threadIdx.x - off] : 0;
    __syncthreads();
    sh[threadIdx.x] += t;
    __syncthreads();
  }
  if (i < n) tmp[i] = sh[threadIdx.x];
  if (threadIdx.x == 255) bsum[blockIdx.x] = sh[255];
}

__global__ void k_scan2(int* __restrict__ bsum, int nb) {
  __shared__ int sh[256];
  __shared__ int carry;
  if (threadIdx.x == 0) carry = 0;
  __syncthreads();
  for (int base = 0; base < nb; base += 256) {
    int i = base + threadIdx.x;
    int v = (i < nb) ? bsum[i] : 0;
    sh[threadIdx.x] = v;
    __syncthreads();
    for (int off = 1; off < 256; off <<= 1) {
      int t = (threadIdx.x >= off) ? sh[threadIdx.x - off] : 0;
      __syncthreads();
      sh[threadIdx.x] += t;
      __syncthreads();
    }
    if (i < nb) bsum[i] = sh[threadIdx.x] + carry;
    __syncthreads();
    if (threadIdx.x == 0) carry += sh[255];
    __syncthreads();
  }
}

__global__ void k_scan3(const int* __restrict__ tmp, const int* __restrict__ deg,
                        const int* __restrict__ bsum, int* __restrict__ rowptr,
                        int* __restrict__ fill, int n) {
  int i = blockIdx.x * 256 + threadIdx.x;
  if (i >= n) return;
  int off = (blockIdx.x > 0) ? bsum[blockIdx.x - 1] : 0;
  int excl = tmp[i] - deg[i] + off;
  rowptr[i] = excl;
  fill[i] = excl;
}

__global__ void k_scatter(const int* __restrict__ ei, int* __restrict__ fill,
                          int* __restrict__ csr_src, const int* __restrict__ flags,
                          int E, int Nn) {
  int i = blockIdx.x * blockDim.x + threadIdx.x;
  if (i >= E) return;
  int is64 = flags[1];
  int s = edge_idx(ei, i, is64);
  int d = edge_idx(ei, (long)E + i, is64);
  if ((unsigned)s >= (unsigned)Nn) s = 0;
  if ((unsigned)d >= (unsigned)Nn) d = 0;
  int pos = atomicAdd(&fill[d], 1);
  csr_src[pos] = s;
}

// ==== fused attention: 1 wave/node; 4 edge-slots x 16 lanes; lane j: dims 8j..8j+7
// (head j>>2); 2-shfl quad reduce; per-slot online softmax; log-sum-exp merge ====
__global__ __launch_bounds__(256) void k_edge(
    const float* __restrict__ q, const float* __restrict__ kk,
    const float* __restrict__ v, const int* __restrict__ rowptr,
    const int* __restrict__ deg, const int* __restrict__ csr_src,
    const float* __restrict__ p_rel, float* __restrict__ agg, int N) {
  int n = (blockIdx.x * 256 + threadIdx.x) >> 6;
  if (n >= N) return;
  const int lane = threadIdx.x & 63;
  const int g = lane >> 4;
  const int j = lane & 15;
  const int start = rowptr[n];
  const int end = start + deg[n];
  const float prl = p_rel[j >> 2] * 0.17677669529663687f;  // 1/sqrt(32)
  const float4 qa = *(const float4*)(q + (size_t)n * CD + 8 * j);
  const float4 qb = *(const float4*)(q + (size_t)n * CD + 8 * j + 4);
  float m = -INFINITY, den = 0.f;
  float acc[8] = {0.f, 0.f, 0.f, 0.f, 0.f, 0.f, 0.f, 0.f};
  for (int e = start + g; e < end; e += 4) {
    int s = csr_src[e];
    const float4* kr = (const float4*)(kk + (size_t)s * CD + 8 * j);
    const float4* vr = (const float4*)(v + (size_t)s * CD + 8 * j);
    float4 ka = kr[0], kb = kr[1];
    float4 va = vr[0], vb = vr[1];
    float pd = qa.x * ka.x + qa.y * ka.y + qa.z * ka.z + qa.w * ka.w +
               qb.x * kb.x + qb.y * kb.y + qb.z * kb.z + qb.w * kb.w;
    pd += __shfl_xor(pd, 1);
    pd += __shfl_xor(pd, 2);
    float a = pd * prl;
    float mn = fmaxf(m, a);
    float sc = __expf(m - mn);
    float ew = __expf(a - mn);
    acc[0] = acc[0] * sc + ew * va.x; acc[1] = acc[1] * sc + ew * va.y;
    acc[2] = acc[2] * sc + ew * va.z; acc[3] = acc[3] * sc + ew * va.w;
    acc[4] = acc[4] * sc + ew * vb.x; acc[5] = acc[5] * sc + ew * vb.y;
    acc[6] = acc[6] * sc + ew * vb.z; acc[7] = acc[7] * sc + ew * vb.w;
    den = den * sc + ew;
    m = mn;
  }
#pragma unroll
  for (int off = 16; off <= 32; off <<= 1) {
    float mo = __shfl_xor(m, off);
    float dno = __shfl_xor(den, off);
    float ao[8];
#pragma unroll
    for (int i = 0; i < 8; i++) ao[i] = __shfl_xor(acc[i], off);
    float mn = fmaxf(m, mo);
    float s1 = (den > 0.f) ? __expf(m - mn) : 0.f;
    float s2 = (dno > 0.f) ? __expf(mo - mn) : 0.f;
#pragma unroll
    for (int i = 0; i < 8; i++) acc[i] = acc[i] * s1 + ao[i] * s2;
    den = den * s1 + dno * s2;
    m = mn;
  }
  if (g == 0) {
    float inv = (den > 0.f) ? 1.f / den : 0.f;
    float4 o0 = make_float4(acc[0] * inv, acc[1] * inv, acc[2] * inv, acc[3] * inv);
    float4 o1 = make_float4(acc[4] * inv, acc[5] * inv, acc[6] * inv, acc[7] * inv);
    *(float4*)(agg + (size_t)n * CD + 8 * j) = o0;
    *(float4*)(agg + (size_t)n * CD + 8 * j + 4) = o1;
  }
}

// ---- out[n,0:2] = h[n,:] @ Wfc + bfc; f32 out if flags[0] else bf16 ----
__global__ __launch_bounds__(256) void k_final(const float* __restrict__ h,
                                               const float* __restrict__ Wfc,
                                               const float* __restrict__ bfc,
                                               void* __restrict__ out,
                                               const int* __restrict__ flags, int N) {
  int g = (blockIdx.x * 256 + threadIdx.x) >> 5;
  int lane = threadIdx.x & 31;
  if (g >= N) return;
  const float* hr = h + (size_t)g * CD;
  float a0 = 0.f, a1 = 0.f;
#pragma unroll
  for (int j = 0; j < 4; j++) {
    float hv = hr[lane + 32 * j];
    a0 += hv * Wfc[(lane + 32 * j) * 2];
    a1 += hv * Wfc[(lane + 32 * j) * 2 + 1];
  }
#pragma unroll
  for (int off = 16; off; off >>= 1) {
    a0 += __shfl_xor(a0, off);
    a1 += __shfl_xor(a1, off);
  }
  if (lane == 0) {
    float o0 = a0 + bfc[0];
    float o1 = a1 + bfc[1];
    if (flags[0]) {
      ((float*)out)[(size_t)g * 2] = o0;
      ((float*)out)[(size_t)g * 2 + 1] = o1;
    } else {
      ((bf16*)out)[(size_t)g * 2] = __float2bfloat16(o0);
      ((bf16*)out)[(size_t)g * 2 + 1] = __float2bfloat16(o1);
    }
  }
}

extern "C" void kernel_launch(void* const* d_in, const int* in_sizes, int n_in,
                              void* d_out, int out_size, void* d_ws, size_t ws_size,
                              hipStream_t stream) {
  const int* ei = (const int*)d_in[1];
  const int N = in_sizes[0] / CD;
  const int E = in_sizes[1] / 2;
  const size_t NC = (size_t)N * CD;
  const int nB = (N + 255) / 256;

  float* p = (float*)d_ws;
  float* hbuf = p;
  float* qbuf = p + NC;
  float* kbuf = p + 2 * NC;
  float* vbuf = p + 3 * NC;
  int* ip = (int*)(p + 4 * NC);
  int* deg = ip;
  int* tmp = ip + N;
  int* rowptr = ip + 2 * N;
  int* fill = ip + 3 * N;
  int* bsum = ip + 4 * N;
  int* csr_src = ip + 4 * N + nB;
  float* cur = (float*)(csr_src + E);
  float* wkeff = cur; cur += (size_t)LL * CD * CD;
  float* bkeff = cur; cur += (size_t)LL * CD;
  float* wveff = cur; cur += (size_t)LL * CD * CD;
  float* bveff = cur; cur += (size_t)LL * CD;
  float* pblock = cur;
  float* pWk = cur; cur += (size_t)LL * CD * CD;
  float* pbk = cur; cur += (size_t)LL * CD;
  float* pWq = cur; cur += (size_t)LL * CD * CD;
  float* pbq = cur; cur += (size_t)LL * CD;
  float* pWv = cur; cur += (size_t)LL * CD * CD;
  float* pbv = cur; cur += (size_t)LL * CD;
  float* par = cur; cur += (size_t)LL * HH * DH * DH;
  float* pmr = cur; cur += (size_t)LL * HH * DH * DH;
  float* ppr = cur; cur += (size_t)LL * HH;
  float* pWa = cur; cur += (size_t)LL * CD * CD;
  float* pba = cur; cur += (size_t)LL * CD;
  float* pskip = cur; cur += LL;
  float* pWfc = cur; cur += (size_t)CD * 2;
  float* pbfc = cur; cur += 2;
  int* flags = (int*)cur;

  k_detect<<<1, 128, 0, stream>>>(d_in[0], ei, flags);
  k_cvt<<<((int)NC + 255) / 256, 256, 0, stream>>>(d_in[0], hbuf, (int)NC, flags);

  SegTab tab;
  const int sizes[NSEG] = {LL * CD * CD, LL * CD, LL * CD * CD, LL * CD,
                           LL * CD * CD, LL * CD, LL * HH * DH * DH,
                           LL * HH * DH * DH, LL * HH, LL * CD * CD, LL * CD,
                           LL, CD * 2, 2};
  const int srcIdx[NSEG] = {2, 3, 4, 5, 6, 7, 8, 9, 10, 11, 12, 13, 14, 15};
  int off = 0;
  for (int k = 0; k < NSEG; k++) {
    tab.src[k] = d_in[srcIdx[k]];
    tab.off[k] = off;
    off += sizes[k];
  }
  tab.total = off;
  k_cvt_params<<<(off + 255) / 256, 256, 0, stream>>>(tab, pblock, flags);

  k_eff<<<dim3(CD + 1, HH, LL * 2), DH, 0, stream>>>(pWk, pbk, pWv, pbv, par, pmr,
                                                     wkeff, bkeff, wveff, bveff);

  hipMemsetAsync(deg, 0, (size_t)N * sizeof(int), stream);
  k_hist<<<(E + 255) / 256, 256, 0, stream>>>(ei, deg, flags, E, N);
  k_scan1<<<nB, 256, 0, stream>>>(deg, tmp, bsum, N);
  k_scan2<<<1, 256, 0, stream>>>(bsum, nB);
  k_scan3<<<nB, 256, 0, stream>>>(tmp, deg, bsum, rowptr, fill, N);
  k_scatter<<<(E + 255) / 256, 256, 0, stream>>>(ei, fill, csr_src, flags, E, N);

  const int gemmBlocks = (N + 127) / 128;
  for (int l = 0; l < LL; l++) {
    k_gemm_t<false, false><<<gemmBlocks, 256, 0, stream>>>(
        hbuf, pWq + (size_t)l * CD * CD, pbq + (size_t)l * CD, qbuf, nullptr, N);
    k_gemm_t<false, false><<<gemmBlocks, 256, 0, stream>>>(
        hbuf, wkeff + (size_t)l * CD * CD, bkeff + (size_t)l * CD, kbuf, nullptr, N);
    k_gemm_t<false, false><<<gemmBlocks, 256, 0, stream>>>(
        hbuf, wveff + (size_t)l * CD * CD, bveff + (size_t)l * CD, vbuf, nullptr, N);

    k_edge<<<(N + 3) / 4, 256, 0, stream>>>(qbuf, kbuf, vbuf, rowptr, deg,
                                            csr_src, ppr + (size_t)l * HH, qbuf, N);

    k_gemm_t<true, true><<<gemmBlocks, 256, 0, stream>>>(
        qbuf, pWa + (size_t)l * CD * CD, pba + (size_t)l * CD, hbuf, pskip + l, N);
  }
  k_final<<<(N + 7) / 8, 256, 0, stream>>>(hbuf, pWfc, pbfc, d_out, flags, N);
}

// Round 8
// 1416.672 us; speedup vs baseline: 18.5260x; 18.5260x over previous
//
#include <hip/hip_runtime.h>
#include <hip/hip_bf16.h>
#include <math.h>

#define CD 128
#define HH 4
#define DH 32
#define LL 2

using bf16 = __hip_bfloat16;

__device__ __forceinline__ float bfbits2f(unsigned int s) {
  return __uint_as_float(s << 16);
}

__device__ __forceinline__ float gelu_f(float x) {
  return 0.5f * x * (1.0f + erff(x * 0.70710678118654752f));
}

// ---- detect input formats: flags[0]=floats-are-f32, flags[1]=edge-index-is-i64 ----
__global__ void k_detect(const void* __restrict__ x, const int* __restrict__ ei,
                         int* __restrict__ flags) {
  __shared__ int cnt_f32, cnt_i32;
  if (threadIdx.x == 0) { cnt_f32 = 0; cnt_i32 = 0; }
  __syncthreads();
  int t = threadIdx.x;  // 128 threads
  unsigned short u = ((const unsigned short*)x)[2 * t];
  float v = bfbits2f((unsigned int)u);
  float av = fabsf(v);
  if (av != 0.f && (av > 1e8f || av < 1e-8f)) atomicAdd(&cnt_f32, 1);
  if (t < 64) {
    if (((const int*)ei)[2 * t + 1] != 0) atomicAdd(&cnt_i32, 1);
  }
  __syncthreads();
  if (threadIdx.x == 0) {
    flags[0] = (cnt_f32 > 8) ? 1 : 0;
    flags[1] = (cnt_i32 == 0) ? 1 : 0;
  }
}

// ---- normalize a float input (bf16 or f32) to f32 ----
__global__ void k_cvt(const void* __restrict__ in, float* __restrict__ out, int n,
                      const int* __restrict__ flags) {
  int i = blockIdx.x * blockDim.x + threadIdx.x;
  if (i >= n) return;
  if (flags[0]) out[i] = ((const float*)in)[i];
  else out[i] = bfbits2f((unsigned int)((const unsigned short*)in)[i]);
}

// ---- all parameter tensors -> contiguous f32 block, one launch ----
#define NSEG 14
struct SegTab {
  const void* src[NSEG];
  int off[NSEG];
  int total;
};
__global__ void k_cvt_params(SegTab tab, float* __restrict__ dst,
                             const int* __restrict__ flags) {
  int i = blockIdx.x * 256 + threadIdx.x;
  if (i >= tab.total) return;
  int seg = 0;
#pragma unroll
  for (int k = 1; k < NSEG; k++)
    if (i >= tab.off[k]) seg = k;
  int j = i - tab.off[seg];
  const void* src = tab.src[seg];
  dst[i] = flags[0] ? ((const float*)src)[j]
                    : bfbits2f((unsigned int)((const unsigned short*)src)[j]);
}

__device__ __forceinline__ int edge_idx(const int* __restrict__ ei, long pos, int is64) {
  return is64 ? ei[2 * pos] : ei[pos];
}

// ---- fold relation transforms into K/V weights+biases, both layers, one launch ----
__global__ void k_eff(const float* __restrict__ Wk, const float* __restrict__ bk,
                      const float* __restrict__ Wv, const float* __restrict__ bv,
                      const float* __restrict__ ar, const float* __restrict__ mr,
                      float* __restrict__ wke, float* __restrict__ bke,
                      float* __restrict__ wve, float* __restrict__ bve) {
  int c = blockIdx.x, h = blockIdx.y, z = blockIdx.z;
  int l = z >> 1, which = z & 1;
  int e = threadIdx.x;
  const float* W = (which ? Wv : Wk) + (size_t)l * CD * CD;
  const float* B = (which ? bv : bk) + (size_t)l * CD;
  const float* R = (which ? mr : ar) + (size_t)l * HH * DH * DH + h * DH * DH;
  float* Wo = (which ? wve : wke) + (size_t)l * CD * CD;
  float* Bo = (which ? bve : bke) + (size_t)l * CD;
  float acc = 0.f;
  if (c < CD) {
#pragma unroll
    for (int d = 0; d < DH; d++) acc += W[c * CD + h * DH + d] * R[d * DH + e];
    Wo[c * CD + h * DH + e] = acc;
  } else {
#pragma unroll
    for (int d = 0; d < DH; d++) acc += B[h * DH + d] * R[d * DH + e];
    Bo[h * DH + e] = acc;
  }
}

// ---- y[N,128] = (GELU?)(x[N,128]) @ W[128,128] + b ; all f32.
// EXACT round-3/4 proven structure (flat, acc[16][4], scalar W loads). ----
template <bool GELU>
__global__ __launch_bounds__(256) void k_gemm(const float* __restrict__ xin,
                                              const float* __restrict__ win,
                                              const float* __restrict__ bin,
                                              float* __restrict__ y, int nrows) {
  __shared__ float xs[128][CD];
  const int t = threadIdx.x;
  const int r0 = blockIdx.x * 128;
#pragma unroll
  for (int it = 0; it < 16; it++) {
    int idx = t + it * 256;       // 4096 float4 chunks
    int r = idx >> 5;             // 32 chunks per row
    int c4 = (idx & 31) * 4;
    int gr = r0 + r;
    float4 f = make_float4(0.f, 0.f, 0.f, 0.f);
    if (gr < nrows) f = *(const float4*)(xin + (size_t)gr * CD + c4);
    if (GELU) {
      f.x = gelu_f(f.x); f.y = gelu_f(f.y);
      f.z = gelu_f(f.z); f.w = gelu_f(f.w);
    }
    *(float4*)&xs[r][c4] = f;
  }
  __syncthreads();
  const int tx = t & 31, ty = t >> 5;  // ty in [0,8)
  float acc[16][4];
#pragma unroll
  for (int rr = 0; rr < 16; rr++)
#pragma unroll
    for (int cc = 0; cc < 4; cc++) acc[rr][cc] = bin[tx + 32 * cc];

  for (int k = 0; k < CD; k++) {
    float wv[4];
#pragma unroll
    for (int cc = 0; cc < 4; cc++) wv[cc] = win[k * CD + tx + 32 * cc];
#pragma unroll
    for (int rr = 0; rr < 16; rr++) {
      float xv = xs[ty * 16 + rr][k];
#pragma unroll
      for (int cc = 0; cc < 4; cc++) acc[rr][cc] += xv * wv[cc];
    }
  }
#pragma unroll
  for (int rr = 0; rr < 16; rr++) {
    int gr = r0 + ty * 16 + rr;
    if (gr < nrows) {
#pragma unroll
      for (int cc = 0; cc < 4; cc++)
        y[(size_t)gr * CD + tx + 32 * cc] = acc[rr][cc];
    }
  }
}

// ---- h = g*out + (1-g)*h ----
__global__ void k_gate(float* __restrict__ h, const float* __restrict__ ob,
                       const float* __restrict__ skip, int n4) {
  int i = blockIdx.x * blockDim.x + threadIdx.x;
  if (i >= n4) return;
  float s = skip[0];
  float g = 1.f / (1.f + __expf(-s));
  float4 hv = ((const float4*)h)[i];
  float4 ov = ((const float4*)ob)[i];
  hv.x = g * ov.x + (1.f - g) * hv.x;
  hv.y = g * ov.y + (1.f - g) * hv.y;
  hv.z = g * ov.z + (1.f - g) * hv.z;
  hv.w = g * ov.w + (1.f - g) * hv.w;
  ((float4*)h)[i] = hv;
}

// ==== CSR build ====
__global__ void k_hist(const int* __restrict__ ei, int* __restrict__ deg,
                       const int* __restrict__ flags, int E, int Nn) {
  int i = blockIdx.x * blockDim.x + threadIdx.x;
  if (i >= E) return;
  int d = edge_idx(ei, (long)E + i, flags[1]);
  if ((unsigned)d >= (unsigned)Nn) d = 0;
  atomicAdd(&deg[d], 1);
}

__global__ void k_scan1(const int* __restrict__ deg, int* __restrict__ tmp,
                        int* __restrict__ bsum, int n) {
  __shared__ int sh[256];
  int i = blockIdx.x * 256 + threadIdx.x;
  int v = (i < n) ? deg[i] : 0;
  sh[threadIdx.x] = v;
  __syncthreads();
  for (int off = 1; off < 256; off <<= 1) {
    int t = (threadIdx.x >= off) ? sh[threadIdx.x - off] : 0;
    __syncthreads();
    sh[threadIdx.x] += t;
    __syncthreads();
  }
  if (i < n) tmp[i] = sh[threadIdx.x];
  if (threadIdx.x == 255) bsum[blockIdx.x] = sh[255];
}

__global__ void k_scan2(int* __restrict__ bsum, int nb) {
  __shared__ int sh[256];
  __shared__ int carry;
  if (threadIdx.x == 0) carry = 0;
  __syncthreads();
  for (int base = 0; base < nb; base += 256) {
    int i = base + threadIdx.x;
    int v = (i < nb) ? bsum[i] : 0;
    sh[threadIdx.x] = v;
    __syncthreads();
    for (int off = 1; off < 256; off <<= 1) {
      int t = (threadIdx.x >= off) ? sh[threadIdx.x - off] : 0;
      __syncthreads();
      sh[threadIdx.x] += t;
      __syncthreads();
    }
    if (i < nb) bsum[i] = sh[threadIdx.x] + carry;
    __syncthreads();
    if (threadIdx.x == 0) carry += sh[255];
    __syncthreads();
  }
}

__global__ void k_scan3(const int* __restrict__ tmp, const int* __restrict__ deg,
                        const int* __restrict__ bsum, int* __restrict__ rowptr,
                        int* __restrict__ fill, int n) {
  int i = blockIdx.x * 256 + threadIdx.x;
  if (i >= n) return;
  int off = (blockIdx.x > 0) ? bsum[blockIdx.x - 1] : 0;
  int excl = tmp[i] - deg[i] + off;
  rowptr[i] = excl;
  fill[i] = excl;
}

__global__ void k_scatter(const int* __restrict__ ei, int* __restrict__ fill,
                          int* __restrict__ csr_src, const int* __restrict__ flags,
                          int E, int Nn) {
  int i = blockIdx.x * blockDim.x + threadIdx.x;
  if (i >= E) return;
  int is64 = flags[1];
  int s = edge_idx(ei, i, is64);
  int d = edge_idx(ei, (long)E + i, is64);
  if ((unsigned)s >= (unsigned)Nn) s = 0;
  if ((unsigned)d >= (unsigned)Nn) d = 0;
  int pos = atomicAdd(&fill[d], 1);
  csr_src[pos] = s;
}

// ==== fused attention: 1 wave/node; 4 edge-slots x 16 lanes; lane j: dims 8j..8j+7
// (head j>>2); 2-shfl quad reduce; per-slot online softmax; log-sum-exp merge ====
__global__ __launch_bounds__(256) void k_edge(
    const float* __restrict__ q, const float* __restrict__ kk,
    const float* __restrict__ v, const int* __restrict__ rowptr,
    const int* __restrict__ deg, const int* __restrict__ csr_src,
    const float* __restrict__ p_rel, float* __restrict__ agg, int N) {
  int n = (blockIdx.x * 256 + threadIdx.x) >> 6;
  if (n >= N) return;
  const int lane = threadIdx.x & 63;
  const int g = lane >> 4;
  const int j = lane & 15;
  const int start = rowptr[n];
  const int end = start + deg[n];
  const float prl = p_rel[j >> 2] * 0.17677669529663687f;  // 1/sqrt(32)
  const float4 qa = *(const float4*)(q + (size_t)n * CD + 8 * j);
  const float4 qb = *(const float4*)(q + (size_t)n * CD + 8 * j + 4);
  float m = -INFINITY, den = 0.f;
  float acc[8] = {0.f, 0.f, 0.f, 0.f, 0.f, 0.f, 0.f, 0.f};
  for (int e = start + g; e < end; e += 4) {
    int s = csr_src[e];
    const float4* kr = (const float4*)(kk + (size_t)s * CD + 8 * j);
    const float4* vr = (const float4*)(v + (size_t)s * CD + 8 * j);
    float4 ka = kr[0], kb = kr[1];
    float4 va = vr[0], vb = vr[1];
    float pd = qa.x * ka.x + qa.y * ka.y + qa.z * ka.z + qa.w * ka.w +
               qb.x * kb.x + qb.y * kb.y + qb.z * kb.z + qb.w * kb.w;
    pd += __shfl_xor(pd, 1);
    pd += __shfl_xor(pd, 2);
    float a = pd * prl;
    float mn = fmaxf(m, a);
    float sc = __expf(m - mn);
    float ew = __expf(a - mn);
    acc[0] = acc[0] * sc + ew * va.x; acc[1] = acc[1] * sc + ew * va.y;
    acc[2] = acc[2] * sc + ew * va.z; acc[3] = acc[3] * sc + ew * va.w;
    acc[4] = acc[4] * sc + ew * vb.x; acc[5] = acc[5] * sc + ew * vb.y;
    acc[6] = acc[6] * sc + ew * vb.z; acc[7] = acc[7] * sc + ew * vb.w;
    den = den * sc + ew;
    m = mn;
  }
#pragma unroll
  for (int off = 16; off <= 32; off <<= 1) {
    float mo = __shfl_xor(m, off);
    float dno = __shfl_xor(den, off);
    float ao[8];
#pragma unroll
    for (int i = 0; i < 8; i++) ao[i] = __shfl_xor(acc[i], off);
    float mn = fmaxf(m, mo);
    float s1 = (den > 0.f) ? __expf(m - mn) : 0.f;
    float s2 = (dno > 0.f) ? __expf(mo - mn) : 0.f;
#pragma unroll
    for (int i = 0; i < 8; i++) acc[i] = acc[i] * s1 + ao[i] * s2;
    den = den * s1 + dno * s2;
    m = mn;
  }
  if (g == 0) {
    float inv = (den > 0.f) ? 1.f / den : 0.f;
    float4 o0 = make_float4(acc[0] * inv, acc[1] * inv, acc[2] * inv, acc[3] * inv);
    float4 o1 = make_float4(acc[4] * inv, acc[5] * inv, acc[6] * inv, acc[7] * inv);
    *(float4*)(agg + (size_t)n * CD + 8 * j) = o0;
    *(float4*)(agg + (size_t)n * CD + 8 * j + 4) = o1;
  }
}

// ---- out[n,0:2] = h[n,:] @ Wfc + bfc; f32 out if flags[0] else bf16 ----
__global__ __launch_bounds__(256) void k_final(const float* __restrict__ h,
                                               const float* __restrict__ Wfc,
                                               const float* __restrict__ bfc,
                                               void* __restrict__ out,
                                               const int* __restrict__ flags, int N) {
  int g = (blockIdx.x * 256 + threadIdx.x) >> 5;
  int lane = threadIdx.x & 31;
  if (g >= N) return;
  const float* hr = h + (size_t)g * CD;
  float a0 = 0.f, a1 = 0.f;
#pragma unroll
  for (int j = 0; j < 4; j++) {
    float hv = hr[lane + 32 * j];
    a0 += hv * Wfc[(lane + 32 * j) * 2];
    a1 += hv * Wfc[(lane + 32 * j) * 2 + 1];
  }
#pragma unroll
  for (int off = 16; off; off >>= 1) {
    a0 += __shfl_xor(a0, off);
    a1 += __shfl_xor(a1, off);
  }
  if (lane == 0) {
    float o0 = a0 + bfc[0];
    float o1 = a1 + bfc[1];
    if (flags[0]) {
      ((float*)out)[(size_t)g * 2] = o0;
      ((float*)out)[(size_t)g * 2 + 1] = o1;
    } else {
      ((bf16*)out)[(size_t)g * 2] = __float2bfloat16(o0);
      ((bf16*)out)[(size_t)g * 2 + 1] = __float2bfloat16(o1);
    }
  }
}

extern "C" void kernel_launch(void* const* d_in, const int* in_sizes, int n_in,
                              void* d_out, int out_size, void* d_ws, size_t ws_size,
                              hipStream_t stream) {
  const int* ei = (const int*)d_in[1];
  const int N = in_sizes[0] / CD;
  const int E = in_sizes[1] / 2;
  const size_t NC = (size_t)N * CD;
  const int nB = (N + 255) / 256;

  float* p = (float*)d_ws;
  float* hbuf = p;
  float* qbuf = p + NC;
  float* kbuf = p + 2 * NC;
  float* vbuf = p + 3 * NC;
  int* ip = (int*)(p + 4 * NC);
  int* deg = ip;
  int* tmp = ip + N;
  int* rowptr = ip + 2 * N;
  int* fill = ip + 3 * N;
  int* bsum = ip + 4 * N;
  int* csr_src = ip + 4 * N + nB;
  float* cur = (float*)(csr_src + E);
  float* wkeff = cur; cur += (size_t)LL * CD * CD;
  float* bkeff = cur; cur += (size_t)LL * CD;
  float* wveff = cur; cur += (size_t)LL * CD * CD;
  float* bveff = cur; cur += (size_t)LL * CD;
  float* pblock = cur;
  float* pWk = cur; cur += (size_t)LL * CD * CD;
  float* pbk = cur; cur += (size_t)LL * CD;
  float* pWq = cur; cur += (size_t)LL * CD * CD;
  float* pbq = cur; cur += (size_t)LL * CD;
  float* pWv = cur; cur += (size_t)LL * CD * CD;
  float* pbv = cur; cur += (size_t)LL * CD;
  float* par = cur; cur += (size_t)LL * HH * DH * DH;
  float* pmr = cur; cur += (size_t)LL * HH * DH * DH;
  float* ppr = cur; cur += (size_t)LL * HH;
  float* pWa = cur; cur += (size_t)LL * CD * CD;
  float* pba = cur; cur += (size_t)LL * CD;
  float* pskip = cur; cur += LL;
  float* pWfc = cur; cur += (size_t)CD * 2;
  float* pbfc = cur; cur += 2;
  int* flags = (int*)cur;

  k_detect<<<1, 128, 0, stream>>>(d_in[0], ei, flags);
  k_cvt<<<((int)NC + 255) / 256, 256, 0, stream>>>(d_in[0], hbuf, (int)NC, flags);

  SegTab tab;
  const int sizes[NSEG] = {LL * CD * CD, LL * CD, LL * CD * CD, LL * CD,
                           LL * CD * CD, LL * CD, LL * HH * DH * DH,
                           LL * HH * DH * DH, LL * HH, LL * CD * CD, LL * CD,
                           LL, CD * 2, 2};
  const int srcIdx[NSEG] = {2, 3, 4, 5, 6, 7, 8, 9, 10, 11, 12, 13, 14, 15};
  int off = 0;
  for (int k = 0; k < NSEG; k++) {
    tab.src[k] = d_in[srcIdx[k]];
    tab.off[k] = off;
    off += sizes[k];
  }
  tab.total = off;
  k_cvt_params<<<(off + 255) / 256, 256, 0, stream>>>(tab, pblock, flags);

  k_eff<<<dim3(CD + 1, HH, LL * 2), DH, 0, stream>>>(pWk, pbk, pWv, pbv, par, pmr,
                                                     wkeff, bkeff, wveff, bveff);

  hipMemsetAsync(deg, 0, (size_t)N * sizeof(int), stream);
  k_hist<<<(E + 255) / 256, 256, 0, stream>>>(ei, deg, flags, E, N);
  k_scan1<<<nB, 256, 0, stream>>>(deg, tmp, bsum, N);
  k_scan2<<<1, 256, 0, stream>>>(bsum, nB);
  k_scan3<<<nB, 256, 0, stream>>>(tmp, deg, bsum, rowptr, fill, N);
  k_scatter<<<(E + 255) / 256, 256, 0, stream>>>(ei, fill, csr_src, flags, E, N);

  const int gemmBlocks = (N + 127) / 128;
  for (int l = 0; l < LL; l++) {
    k_gemm<false><<<gemmBlocks, 256, 0, stream>>>(
        hbuf, pWq + (size_t)l * CD * CD, pbq + (size_t)l * CD, qbuf, N);
    k_gemm<false><<<gemmBlocks, 256, 0, stream>>>(
        hbuf, wkeff + (size_t)l * CD * CD, bkeff + (size_t)l * CD, kbuf, N);
    k_gemm<false><<<gemmBlocks, 256, 0, stream>>>(
        hbuf, wveff + (size_t)l * CD * CD, bveff + (size_t)l * CD, vbuf, N);

    k_edge<<<(N + 3) / 4, 256, 0, stream>>>(qbuf, kbuf, vbuf, rowptr, deg,
                                            csr_src, ppr + (size_t)l * HH, qbuf, N);

    // out = gelu(agg) @ Wa + ba -> kbuf; then gated residual into hbuf
    k_gemm<true><<<gemmBlocks, 256, 0, stream>>>(
        qbuf, pWa + (size_t)l * CD * CD, pba + (size_t)l * CD, kbuf, N);
    k_gate<<<((int)(NC / 4) + 255) / 256, 256, 0, stream>>>(hbuf, kbuf, pskip + l,
                                                            (int)(NC / 4));
  }
  k_final<<<(N + 7) / 8, 256, 0, stream>>>(hbuf, pWfc, pbfc, d_out, flags, N);
}

// Round 9
// 1156.615 us; speedup vs baseline: 22.6915x; 1.2248x over previous
//
#include <hip/hip_runtime.h>
#include <hip/hip_bf16.h>
#include <math.h>

#define CD 128
#define HH 4
#define DH 32
#define LL 2

using bf16 = __hip_bfloat16;

__device__ __forceinline__ float bfbits2f(unsigned int s) {
  return __uint_as_float(s << 16);
}

__device__ __forceinline__ unsigned short f2bfbits(float f) {
  unsigned int u = __float_as_uint(f);
  unsigned int r = (u + 0x7fff + ((u >> 16) & 1)) >> 16;  // RNE
  return (unsigned short)r;
}

__device__ __forceinline__ float gelu_f(float x) {
  return 0.5f * x * (1.0f + erff(x * 0.70710678118654752f));
}

// ---- detect input formats: flags[0]=floats-are-f32, flags[1]=edge-index-is-i64 ----
__global__ void k_detect(const void* __restrict__ x, const int* __restrict__ ei,
                         int* __restrict__ flags) {
  __shared__ int cnt_f32, cnt_i32;
  if (threadIdx.x == 0) { cnt_f32 = 0; cnt_i32 = 0; }
  __syncthreads();
  int t = threadIdx.x;  // 128 threads
  unsigned short u = ((const unsigned short*)x)[2 * t];
  float v = bfbits2f((unsigned int)u);
  float av = fabsf(v);
  if (av != 0.f && (av > 1e8f || av < 1e-8f)) atomicAdd(&cnt_f32, 1);
  if (t < 64) {
    if (((const int*)ei)[2 * t + 1] != 0) atomicAdd(&cnt_i32, 1);
  }
  __syncthreads();
  if (threadIdx.x == 0) {
    flags[0] = (cnt_f32 > 8) ? 1 : 0;
    flags[1] = (cnt_i32 == 0) ? 1 : 0;
  }
}

// ---- normalize a float input (bf16 or f32) to f32 ----
__global__ void k_cvt(const void* __restrict__ in, float* __restrict__ out, int n,
                      const int* __restrict__ flags) {
  int i = blockIdx.x * blockDim.x + threadIdx.x;
  if (i >= n) return;
  if (flags[0]) out[i] = ((const float*)in)[i];
  else out[i] = bfbits2f((unsigned int)((const unsigned short*)in)[i]);
}

// ---- all parameter tensors -> contiguous f32 block, one launch ----
#define NSEG 14
struct SegTab {
  const void* src[NSEG];
  int off[NSEG];
  int total;
};
__global__ void k_cvt_params(SegTab tab, float* __restrict__ dst,
                             const int* __restrict__ flags) {
  int i = blockIdx.x * 256 + threadIdx.x;
  if (i >= tab.total) return;
  int seg = 0;
#pragma unroll
  for (int k = 1; k < NSEG; k++)
    if (i >= tab.off[k]) seg = k;
  int j = i - tab.off[seg];
  const void* src = tab.src[seg];
  dst[i] = flags[0] ? ((const float*)src)[j]
                    : bfbits2f((unsigned int)((const unsigned short*)src)[j]);
}

__device__ __forceinline__ int edge_idx(const int* __restrict__ ei, long pos, int is64) {
  return is64 ? ei[2 * pos] : ei[pos];
}

// ---- fold relation transforms into K/V weights+biases, both layers, one launch ----
__global__ void k_eff(const float* __restrict__ Wk, const float* __restrict__ bk,
                      const float* __restrict__ Wv, const float* __restrict__ bv,
                      const float* __restrict__ ar, const float* __restrict__ mr,
                      float* __restrict__ wke, float* __restrict__ bke,
                      float* __restrict__ wve, float* __restrict__ bve) {
  int c = blockIdx.x, h = blockIdx.y, z = blockIdx.z;
  int l = z >> 1, which = z & 1;
  int e = threadIdx.x;
  const float* W = (which ? Wv : Wk) + (size_t)l * CD * CD;
  const float* B = (which ? bv : bk) + (size_t)l * CD;
  const float* R = (which ? mr : ar) + (size_t)l * HH * DH * DH + h * DH * DH;
  float* Wo = (which ? wve : wke) + (size_t)l * CD * CD;
  float* Bo = (which ? bve : bke) + (size_t)l * CD;
  float acc = 0.f;
  if (c < CD) {
#pragma unroll
    for (int d = 0; d < DH; d++) acc += W[c * CD + h * DH + d] * R[d * DH + e];
    Wo[c * CD + h * DH + e] = acc;
  } else {
#pragma unroll
    for (int d = 0; d < DH; d++) acc += B[h * DH + d] * R[d * DH + e];
    Bo[h * DH + e] = acc;
  }
}

// ---- y[N,128] = (GELU?)(x[N,128]) @ W[128,128] + b ; proven flat structure.
// Epilogue options: OUT_BF16 (pack to bf16), GATE (sigmoid-gated residual into y). ----
template <bool GELU, bool GATE, bool OUT_BF16>
__global__ __launch_bounds__(256) void k_gemm(const float* __restrict__ xin,
                                              const float* __restrict__ win,
                                              const float* __restrict__ bin,
                                              void* __restrict__ yv,
                                              const float* __restrict__ skip,
                                              int nrows) {
  __shared__ float xs[128][CD];
  const int t = threadIdx.x;
  const int r0 = blockIdx.x * 128;
#pragma unroll
  for (int it = 0; it < 16; it++) {
    int idx = t + it * 256;       // 4096 float4 chunks
    int r = idx >> 5;             // 32 chunks per row
    int c4 = (idx & 31) * 4;
    int gr = r0 + r;
    float4 f = make_float4(0.f, 0.f, 0.f, 0.f);
    if (gr < nrows) f = *(const float4*)(xin + (size_t)gr * CD + c4);
    if (GELU) {
      f.x = gelu_f(f.x); f.y = gelu_f(f.y);
      f.z = gelu_f(f.z); f.w = gelu_f(f.w);
    }
    *(float4*)&xs[r][c4] = f;
  }
  __syncthreads();
  const int tx = t & 31, ty = t >> 5;  // ty in [0,8)
  float acc[16][4];
#pragma unroll
  for (int rr = 0; rr < 16; rr++)
#pragma unroll
    for (int cc = 0; cc < 4; cc++) acc[rr][cc] = bin[tx + 32 * cc];

  for (int k = 0; k < CD; k++) {
    float wv[4];
#pragma unroll
    for (int cc = 0; cc < 4; cc++) wv[cc] = win[k * CD + tx + 32 * cc];
#pragma unroll
    for (int rr = 0; rr < 16; rr++) {
      float xv = xs[ty * 16 + rr][k];
#pragma unroll
      for (int cc = 0; cc < 4; cc++) acc[rr][cc] += xv * wv[cc];
    }
  }
  float gg = 0.f;
  if (GATE) gg = 1.f / (1.f + __expf(-skip[0]));
#pragma unroll
  for (int rr = 0; rr < 16; rr++) {
    int gr = r0 + ty * 16 + rr;
    if (gr < nrows) {
#pragma unroll
      for (int cc = 0; cc < 4; cc++) {
        float val = acc[rr][cc];
        if (OUT_BF16) {
          unsigned short* y = (unsigned short*)yv;
          y[(size_t)gr * CD + tx + 32 * cc] = f2bfbits(val);
        } else {
          float* y = (float*)yv;
          size_t ix = (size_t)gr * CD + tx + 32 * cc;
          if (GATE) val = gg * val + (1.f - gg) * y[ix];
          y[ix] = val;
        }
      }
    }
  }
}

// ==== CSR build ====
__global__ void k_hist(const int* __restrict__ ei, int* __restrict__ deg,
                       const int* __restrict__ flags, int E, int Nn) {
  int i = blockIdx.x * blockDim.x + threadIdx.x;
  if (i >= E) return;
  int d = edge_idx(ei, (long)E + i, flags[1]);
  if ((unsigned)d >= (unsigned)Nn) d = 0;
  atomicAdd(&deg[d], 1);
}

__global__ void k_scan1(const int* __restrict__ deg, int* __restrict__ tmp,
                        int* __restrict__ bsum, int n) {
  __shared__ int sh[256];
  int i = blockIdx.x * 256 + threadIdx.x;
  int v = (i < n) ? deg[i] : 0;
  sh[threadIdx.x] = v;
  __syncthreads();
  for (int off = 1; off < 256; off <<= 1) {
    int t = (threadIdx.x >= off) ? sh[threadIdx.x - off] : 0;
    __syncthreads();
    sh[threadIdx.x] += t;
    __syncthreads();
  }
  if (i < n) tmp[i] = sh[threadIdx.x];
  if (threadIdx.x == 255) bsum[blockIdx.x] = sh[255];
}

__global__ void k_scan2(int* __restrict__ bsum, int nb) {
  __shared__ int sh[256];
  __shared__ int carry;
  if (threadIdx.x == 0) carry = 0;
  __syncthreads();
  for (int base = 0; base < nb; base += 256) {
    int i = base + threadIdx.x;
    int v = (i < nb) ? bsum[i] : 0;
    sh[threadIdx.x] = v;
    __syncthreads();
    for (int off = 1; off < 256; off <<= 1) {
      int t = (threadIdx.x >= off) ? sh[threadIdx.x - off] : 0;
      __syncthreads();
      sh[threadIdx.x] += t;
      __syncthreads();
    }
    if (i < nb) bsum[i] = sh[threadIdx.x] + carry;
    __syncthreads();
    if (threadIdx.x == 0) carry += sh[255];
    __syncthreads();
  }
}

__global__ void k_scan3(const int* __restrict__ tmp, const int* __restrict__ deg,
                        const int* __restrict__ bsum, int* __restrict__ rowptr,
                        int* __restrict__ fill, int n) {
  int i = blockIdx.x * 256 + threadIdx.x;
  if (i >= n) return;
  int off = (blockIdx.x > 0) ? bsum[blockIdx.x - 1] : 0;
  int excl = tmp[i] - deg[i] + off;
  rowptr[i] = excl;
  fill[i] = excl;
}

__global__ void k_scatter(const int* __restrict__ ei, int* __restrict__ fill,
                          int* __restrict__ csr_src, const int* __restrict__ flags,
                          int E, int Nn) {
  int i = blockIdx.x * blockDim.x + threadIdx.x;
  if (i >= E) return;
  int is64 = flags[1];
  int s = edge_idx(ei, i, is64);
  int d = edge_idx(ei, (long)E + i, is64);
  if ((unsigned)s >= (unsigned)Nn) s = 0;
  if ((unsigned)d >= (unsigned)Nn) d = 0;
  int pos = atomicAdd(&fill[d], 1);
  csr_src[pos] = s;
}

// ==== fused attention, k/v gathered as bf16 (half the bytes of round 8).
// 1 wave/node; 4 edge-slots x 16 lanes; lane j: dims 8j..8j+7 (head j>>2). ====
__global__ __launch_bounds__(256) void k_edge(
    const float* __restrict__ q, const unsigned short* __restrict__ kk,
    const unsigned short* __restrict__ v, const int* __restrict__ rowptr,
    const int* __restrict__ deg, const int* __restrict__ csr_src,
    const float* __restrict__ p_rel, float* __restrict__ agg, int N) {
  int n = (blockIdx.x * 256 + threadIdx.x) >> 6;
  if (n >= N) return;
  const int lane = threadIdx.x & 63;
  const int g = lane >> 4;
  const int j = lane & 15;
  const int start = rowptr[n];
  const int end = start + deg[n];
  const float prl = p_rel[j >> 2] * 0.17677669529663687f;  // 1/sqrt(32)
  const float4 qa = *(const float4*)(q + (size_t)n * CD + 8 * j);
  const float4 qb = *(const float4*)(q + (size_t)n * CD + 8 * j + 4);
  float m = -INFINITY, den = 0.f;
  float acc[8] = {0.f, 0.f, 0.f, 0.f, 0.f, 0.f, 0.f, 0.f};
  for (int e = start + g; e < end; e += 4) {
    int s = csr_src[e];
    uint4 ku = *(const uint4*)(kk + (size_t)s * CD + 8 * j);  // 8 bf16 = 16 B
    uint4 vu = *(const uint4*)(v + (size_t)s * CD + 8 * j);
    float k0 = bfbits2f(ku.x & 0xffffu), k1 = bfbits2f(ku.x >> 16);
    float k2 = bfbits2f(ku.y & 0xffffu), k3 = bfbits2f(ku.y >> 16);
    float k4 = bfbits2f(ku.z & 0xffffu), k5 = bfbits2f(ku.z >> 16);
    float k6 = bfbits2f(ku.w & 0xffffu), k7 = bfbits2f(ku.w >> 16);
    float v0 = bfbits2f(vu.x & 0xffffu), v1 = bfbits2f(vu.x >> 16);
    float v2 = bfbits2f(vu.y & 0xffffu), v3 = bfbits2f(vu.y >> 16);
    float v4 = bfbits2f(vu.z & 0xffffu), v5 = bfbits2f(vu.z >> 16);
    float v6 = bfbits2f(vu.w & 0xffffu), v7 = bfbits2f(vu.w >> 16);
    float pd = qa.x * k0 + qa.y * k1 + qa.z * k2 + qa.w * k3 +
               qb.x * k4 + qb.y * k5 + qb.z * k6 + qb.w * k7;
    pd += __shfl_xor(pd, 1);
    pd += __shfl_xor(pd, 2);
    float a = pd * prl;
    float mn = fmaxf(m, a);
    float sc = __expf(m - mn);
    float ew = __expf(a - mn);
    acc[0] = acc[0] * sc + ew * v0; acc[1] = acc[1] * sc + ew * v1;
    acc[2] = acc[2] * sc + ew * v2; acc[3] = acc[3] * sc + ew * v3;
    acc[4] = acc[4] * sc + ew * v4; acc[5] = acc[5] * sc + ew * v5;
    acc[6] = acc[6] * sc + ew * v6; acc[7] = acc[7] * sc + ew * v7;
    den = den * sc + ew;
    m = mn;
  }
#pragma unroll
  for (int off = 16; off <= 32; off <<= 1) {
    float mo = __shfl_xor(m, off);
    float dno = __shfl_xor(den, off);
    float ao[8];
#pragma unroll
    for (int i = 0; i < 8; i++) ao[i] = __shfl_xor(acc[i], off);
    float mn = fmaxf(m, mo);
    float s1 = (den > 0.f) ? __expf(m - mn) : 0.f;
    float s2 = (dno > 0.f) ? __expf(mo - mn) : 0.f;
#pragma unroll
    for (int i = 0; i < 8; i++) acc[i] = acc[i] * s1 + ao[i] * s2;
    den = den * s1 + dno * s2;
    m = mn;
  }
  if (g == 0) {
    float inv = (den > 0.f) ? 1.f / den : 0.f;
    float4 o0 = make_float4(acc[0] * inv, acc[1] * inv, acc[2] * inv, acc[3] * inv);
    float4 o1 = make_float4(acc[4] * inv, acc[5] * inv, acc[6] * inv, acc[7] * inv);
    *(float4*)(agg + (size_t)n * CD + 8 * j) = o0;
    *(float4*)(agg + (size_t)n * CD + 8 * j + 4) = o1;
  }
}

// ---- out[n,0:2] = h[n,:] @ Wfc + bfc; f32 out if flags[0] else bf16 ----
__global__ __launch_bounds__(256) void k_final(const float* __restrict__ h,
                                               const float* __restrict__ Wfc,
                                               const float* __restrict__ bfc,
                                               void* __restrict__ out,
                                               const int* __restrict__ flags, int N) {
  int g = (blockIdx.x * 256 + threadIdx.x) >> 5;
  int lane = threadIdx.x & 31;
  if (g >= N) return;
  const float* hr = h + (size_t)g * CD;
  float a0 = 0.f, a1 = 0.f;
#pragma unroll
  for (int j = 0; j < 4; j++) {
    float hv = hr[lane + 32 * j];
    a0 += hv * Wfc[(lane + 32 * j) * 2];
    a1 += hv * Wfc[(lane + 32 * j) * 2 + 1];
  }
#pragma unroll
  for (int off = 16; off; off >>= 1) {
    a0 += __shfl_xor(a0, off);
    a1 += __shfl_xor(a1, off);
  }
  if (lane == 0) {
    float o0 = a0 + bfc[0];
    float o1 = a1 + bfc[1];
    if (flags[0]) {
      ((float*)out)[(size_t)g * 2] = o0;
      ((float*)out)[(size_t)g * 2 + 1] = o1;
    } else {
      ((bf16*)out)[(size_t)g * 2] = __float2bfloat16(o0);
      ((bf16*)out)[(size_t)g * 2 + 1] = __float2bfloat16(o1);
    }
  }
}

extern "C" void kernel_launch(void* const* d_in, const int* in_sizes, int n_in,
                              void* d_out, int out_size, void* d_ws, size_t ws_size,
                              hipStream_t stream) {
  const int* ei = (const int*)d_in[1];
  const int N = in_sizes[0] / CD;
  const int E = in_sizes[1] / 2;
  const size_t NC = (size_t)N * CD;
  const int nB = (N + 255) / 256;

  float* p = (float*)d_ws;
  float* hbuf = p;
  float* qbuf = p + NC;                 // q, reused as agg (f32)
  float* kbuf = p + 2 * NC;             // bf16 k lives in first half
  float* vbuf = p + 3 * NC;             // bf16 v lives in first half
  int* ip = (int*)(p + 4 * NC);
  int* deg = ip;
  int* tmp = ip + N;
  int* rowptr = ip + 2 * N;
  int* fill = ip + 3 * N;
  int* bsum = ip + 4 * N;
  int* csr_src = ip + 4 * N + nB;
  float* cur = (float*)(csr_src + E);
  float* wkeff = cur; cur += (size_t)LL * CD * CD;
  float* bkeff = cur; cur += (size_t)LL * CD;
  float* wveff = cur; cur += (size_t)LL * CD * CD;
  float* bveff = cur; cur += (size_t)LL * CD;
  float* pblock = cur;
  float* pWk = cur; cur += (size_t)LL * CD * CD;
  float* pbk = cur; cur += (size_t)LL * CD;
  float* pWq = cur; cur += (size_t)LL * CD * CD;
  float* pbq = cur; cur += (size_t)LL * CD;
  float* pWv = cur; cur += (size_t)LL * CD * CD;
  float* pbv = cur; cur += (size_t)LL * CD;
  float* par = cur; cur += (size_t)LL * HH * DH * DH;
  float* pmr = cur; cur += (size_t)LL * HH * DH * DH;
  float* ppr = cur; cur += (size_t)LL * HH;
  float* pWa = cur; cur += (size_t)LL * CD * CD;
  float* pba = cur; cur += (size_t)LL * CD;
  float* pskip = cur; cur += LL;
  float* pWfc = cur; cur += (size_t)CD * 2;
  float* pbfc = cur; cur += 2;
  int* flags = (int*)cur;

  k_detect<<<1, 128, 0, stream>>>(d_in[0], ei, flags);
  k_cvt<<<((int)NC + 255) / 256, 256, 0, stream>>>(d_in[0], hbuf, (int)NC, flags);

  SegTab tab;
  const int sizes[NSEG] = {LL * CD * CD, LL * CD, LL * CD * CD, LL * CD,
                           LL * CD * CD, LL * CD, LL * HH * DH * DH,
                           LL * HH * DH * DH, LL * HH, LL * CD * CD, LL * CD,
                           LL, CD * 2, 2};
  const int srcIdx[NSEG] = {2, 3, 4, 5, 6, 7, 8, 9, 10, 11, 12, 13, 14, 15};
  int off = 0;
  for (int k = 0; k < NSEG; k++) {
    tab.src[k] = d_in[srcIdx[k]];
    tab.off[k] = off;
    off += sizes[k];
  }
  tab.total = off;
  k_cvt_params<<<(off + 255) / 256, 256, 0, stream>>>(tab, pblock, flags);

  k_eff<<<dim3(CD + 1, HH, LL * 2), DH, 0, stream>>>(pWk, pbk, pWv, pbv, par, pmr,
                                                     wkeff, bkeff, wveff, bveff);

  hipMemsetAsync(deg, 0, (size_t)N * sizeof(int), stream);
  k_hist<<<(E + 255) / 256, 256, 0, stream>>>(ei, deg, flags, E, N);
  k_scan1<<<nB, 256, 0, stream>>>(deg, tmp, bsum, N);
  k_scan2<<<1, 256, 0, stream>>>(bsum, nB);
  k_scan3<<<nB, 256, 0, stream>>>(tmp, deg, bsum, rowptr, fill, N);
  k_scatter<<<(E + 255) / 256, 256, 0, stream>>>(ei, fill, csr_src, flags, E, N);

  const int gemmBlocks = (N + 127) / 128;
  for (int l = 0; l < LL; l++) {
    // q (f32), k/v (bf16 out) projections — proven flat GEMM
    k_gemm<false, false, false><<<gemmBlocks, 256, 0, stream>>>(
        hbuf, pWq + (size_t)l * CD * CD, pbq + (size_t)l * CD, qbuf, nullptr, N);
    k_gemm<false, false, true><<<gemmBlocks, 256, 0, stream>>>(
        hbuf, wkeff + (size_t)l * CD * CD, bkeff + (size_t)l * CD, kbuf, nullptr, N);
    k_gemm<false, false, true><<<gemmBlocks, 256, 0, stream>>>(
        hbuf, wveff + (size_t)l * CD * CD, bveff + (size_t)l * CD, vbuf, nullptr, N);

    k_edge<<<(N + 3) / 4, 256, 0, stream>>>(
        qbuf, (const unsigned short*)kbuf, (const unsigned short*)vbuf, rowptr,
        deg, csr_src, ppr + (size_t)l * HH, qbuf, N);

    // gelu(agg) @ Wa + ba, gated residual fused into hbuf
    k_gemm<true, true, false><<<gemmBlocks, 256, 0, stream>>>(
        qbuf, pWa + (size_t)l * CD * CD, pba + (size_t)l * CD, hbuf, pskip + l, N);
  }
  k_final<<<(N + 7) / 8, 256, 0, stream>>>(hbuf, pWfc, pbfc, d_out, flags, N);
}

// Round 10
// 1135.192 us; speedup vs baseline: 23.1197x; 1.0189x over previous
//
#include <hip/hip_runtime.h>
#include <hip/hip_bf16.h>
#include <math.h>

#define CD 128
#define HH 4
#define DH 32
#define LL 2

using bf16 = __hip_bfloat16;

__device__ __forceinline__ float bfbits2f(unsigned int s) {
  return __uint_as_float(s << 16);
}

__device__ __forceinline__ unsigned short f2bfbits(float f) {
  unsigned int u = __float_as_uint(f);
  unsigned int r = (u + 0x7fff + ((u >> 16) & 1)) >> 16;  // RNE
  return (unsigned short)r;
}

__device__ __forceinline__ float gelu_f(float x) {
  return 0.5f * x * (1.0f + erff(x * 0.70710678118654752f));
}

// ---- detect input formats: flags[0]=floats-are-f32, flags[1]=edge-index-is-i64 ----
__global__ void k_detect(const void* __restrict__ x, const int* __restrict__ ei,
                         int* __restrict__ flags) {
  __shared__ int cnt_f32, cnt_i32;
  if (threadIdx.x == 0) { cnt_f32 = 0; cnt_i32 = 0; }
  __syncthreads();
  int t = threadIdx.x;  // 128 threads
  unsigned short u = ((const unsigned short*)x)[2 * t];
  float v = bfbits2f((unsigned int)u);
  float av = fabsf(v);
  if (av != 0.f && (av > 1e8f || av < 1e-8f)) atomicAdd(&cnt_f32, 1);
  if (t < 64) {
    if (((const int*)ei)[2 * t + 1] != 0) atomicAdd(&cnt_i32, 1);
  }
  __syncthreads();
  if (threadIdx.x == 0) {
    flags[0] = (cnt_f32 > 8) ? 1 : 0;
    flags[1] = (cnt_i32 == 0) ? 1 : 0;
  }
}

// ---- normalize a float input (bf16 or f32) to f32 ----
__global__ void k_cvt(const void* __restrict__ in, float* __restrict__ out, int n,
                      const int* __restrict__ flags) {
  int i = blockIdx.x * blockDim.x + threadIdx.x;
  if (i >= n) return;
  if (flags[0]) out[i] = ((const float*)in)[i];
  else out[i] = bfbits2f((unsigned int)((const unsigned short*)in)[i]);
}

// ---- all parameter tensors -> contiguous f32 block, one launch ----
#define NSEG 14
struct SegTab {
  const void* src[NSEG];
  int off[NSEG];
  int total;
};
__global__ void k_cvt_params(SegTab tab, float* __restrict__ dst,
                             const int* __restrict__ flags) {
  int i = blockIdx.x * 256 + threadIdx.x;
  if (i >= tab.total) return;
  int seg = 0;
#pragma unroll
  for (int k = 1; k < NSEG; k++)
    if (i >= tab.off[k]) seg = k;
  int j = i - tab.off[seg];
  const void* src = tab.src[seg];
  dst[i] = flags[0] ? ((const float*)src)[j]
                    : bfbits2f((unsigned int)((const unsigned short*)src)[j]);
}

__device__ __forceinline__ int edge_idx(const int* __restrict__ ei, long pos, int is64) {
  return is64 ? ei[2 * pos] : ei[pos];
}

// ---- fold relation transforms into K/V weights+biases, both layers, one launch ----
__global__ void k_eff(const float* __restrict__ Wk, const float* __restrict__ bk,
                      const float* __restrict__ Wv, const float* __restrict__ bv,
                      const float* __restrict__ ar, const float* __restrict__ mr,
                      float* __restrict__ wke, float* __restrict__ bke,
                      float* __restrict__ wve, float* __restrict__ bve) {
  int c = blockIdx.x, h = blockIdx.y, z = blockIdx.z;
  int l = z >> 1, which = z & 1;
  int e = threadIdx.x;
  const float* W = (which ? Wv : Wk) + (size_t)l * CD * CD;
  const float* B = (which ? bv : bk) + (size_t)l * CD;
  const float* R = (which ? mr : ar) + (size_t)l * HH * DH * DH + h * DH * DH;
  float* Wo = (which ? wve : wke) + (size_t)l * CD * CD;
  float* Bo = (which ? bve : bke) + (size_t)l * CD;
  float acc = 0.f;
  if (c < CD) {
#pragma unroll
    for (int d = 0; d < DH; d++) acc += W[c * CD + h * DH + d] * R[d * DH + e];
    Wo[c * CD + h * DH + e] = acc;
  } else {
#pragma unroll
    for (int d = 0; d < DH; d++) acc += B[h * DH + d] * R[d * DH + e];
    Bo[h * DH + e] = acc;
  }
}

// ---- y[N,128] = (GELU?)(x[N,128]) @ W[128,128] + b ; proven flat structure.
// Round-10 change ONLY: thread covers 4 contiguous cols (4tx..4tx+3) so W loads
// are one dwordx4/k-step and C-writes are float4 / packed 8B. ----
template <bool GELU, bool GATE, bool OUT_BF16>
__global__ __launch_bounds__(256) void k_gemm(const float* __restrict__ xin,
                                              const float* __restrict__ win,
                                              const float* __restrict__ bin,
                                              void* __restrict__ yv,
                                              const float* __restrict__ skip,
                                              int nrows) {
  __shared__ float xs[128][CD];
  const int t = threadIdx.x;
  const int r0 = blockIdx.x * 128;
#pragma unroll
  for (int it = 0; it < 16; it++) {
    int idx = t + it * 256;       // 4096 float4 chunks
    int r = idx >> 5;             // 32 chunks per row
    int c4 = (idx & 31) * 4;
    int gr = r0 + r;
    float4 f = make_float4(0.f, 0.f, 0.f, 0.f);
    if (gr < nrows) f = *(const float4*)(xin + (size_t)gr * CD + c4);
    if (GELU) {
      f.x = gelu_f(f.x); f.y = gelu_f(f.y);
      f.z = gelu_f(f.z); f.w = gelu_f(f.w);
    }
    *(float4*)&xs[r][c4] = f;
  }
  __syncthreads();
  const int tx = t & 31, ty = t >> 5;  // ty in [0,8); cols 4tx..4tx+3
  float acc[16][4];
  {
    float4 bv4 = *(const float4*)(bin + 4 * tx);
#pragma unroll
    for (int rr = 0; rr < 16; rr++) {
      acc[rr][0] = bv4.x; acc[rr][1] = bv4.y;
      acc[rr][2] = bv4.z; acc[rr][3] = bv4.w;
    }
  }

  for (int k = 0; k < CD; k++) {
    float4 wv4 = *(const float4*)(win + (size_t)k * CD + 4 * tx);
    float wv[4] = {wv4.x, wv4.y, wv4.z, wv4.w};
#pragma unroll
    for (int rr = 0; rr < 16; rr++) {
      float xv = xs[ty * 16 + rr][k];
#pragma unroll
      for (int cc = 0; cc < 4; cc++) acc[rr][cc] += xv * wv[cc];
    }
  }
  float gg = 0.f;
  if (GATE) gg = 1.f / (1.f + __expf(-skip[0]));
#pragma unroll
  for (int rr = 0; rr < 16; rr++) {
    int gr = r0 + ty * 16 + rr;
    if (gr < nrows) {
      if (OUT_BF16) {
        unsigned short* y = (unsigned short*)yv;
        ushort4 o;
        o.x = f2bfbits(acc[rr][0]); o.y = f2bfbits(acc[rr][1]);
        o.z = f2bfbits(acc[rr][2]); o.w = f2bfbits(acc[rr][3]);
        *(ushort4*)(y + (size_t)gr * CD + 4 * tx) = o;
      } else {
        float* y = (float*)yv;
        float* yp = y + (size_t)gr * CD + 4 * tx;
        float4 o = make_float4(acc[rr][0], acc[rr][1], acc[rr][2], acc[rr][3]);
        if (GATE) {
          float4 h4 = *(const float4*)yp;
          o.x = gg * o.x + (1.f - gg) * h4.x;
          o.y = gg * o.y + (1.f - gg) * h4.y;
          o.z = gg * o.z + (1.f - gg) * h4.z;
          o.w = gg * o.w + (1.f - gg) * h4.w;
        }
        *(float4*)yp = o;
      }
    }
  }
}

// ==== CSR build ====
__global__ void k_hist(const int* __restrict__ ei, int* __restrict__ deg,
                       const int* __restrict__ flags, int E, int Nn) {
  int i = blockIdx.x * blockDim.x + threadIdx.x;
  if (i >= E) return;
  int d = edge_idx(ei, (long)E + i, flags[1]);
  if ((unsigned)d >= (unsigned)Nn) d = 0;
  atomicAdd(&deg[d], 1);
}

__global__ void k_scan1(const int* __restrict__ deg, int* __restrict__ tmp,
                        int* __restrict__ bsum, int n) {
  __shared__ int sh[256];
  int i = blockIdx.x * 256 + threadIdx.x;
  int v = (i < n) ? deg[i] : 0;
  sh[threadIdx.x] = v;
  __syncthreads();
  for (int off = 1; off < 256; off <<= 1) {
    int t = (threadIdx.x >= off) ? sh[threadIdx.x - off] : 0;
    __syncthreads();
    sh[threadIdx.x] += t;
    __syncthreads();
  }
  if (i < n) tmp[i] = sh[threadIdx.x];
  if (threadIdx.x == 255) bsum[blockIdx.x] = sh[255];
}

__global__ void k_scan2(int* __restrict__ bsum, int nb) {
  __shared__ int sh[256];
  __shared__ int carry;
  if (threadIdx.x == 0) carry = 0;
  __syncthreads();
  for (int base = 0; base < nb; base += 256) {
    int i = base + threadIdx.x;
    int v = (i < nb) ? bsum[i] : 0;
    sh[threadIdx.x] = v;
    __syncthreads();
    for (int off = 1; off < 256; off <<= 1) {
      int t = (threadIdx.x >= off) ? sh[threadIdx.x - off] : 0;
      __syncthreads();
      sh[threadIdx.x] += t;
      __syncthreads();
    }
    if (i < nb) bsum[i] = sh[threadIdx.x] + carry;
    __syncthreads();
    if (threadIdx.x == 0) carry += sh[255];
    __syncthreads();
  }
}

__global__ void k_scan3(const int* __restrict__ tmp, const int* __restrict__ deg,
                        const int* __restrict__ bsum, int* __restrict__ rowptr,
                        int* __restrict__ fill, int n) {
  int i = blockIdx.x * 256 + threadIdx.x;
  if (i >= n) return;
  int off = (blockIdx.x > 0) ? bsum[blockIdx.x - 1] : 0;
  int excl = tmp[i] - deg[i] + off;
  rowptr[i] = excl;
  fill[i] = excl;
}

__global__ void k_scatter(const int* __restrict__ ei, int* __restrict__ fill,
                          int* __restrict__ csr_src, const int* __restrict__ flags,
                          int E, int Nn) {
  int i = blockIdx.x * blockDim.x + threadIdx.x;
  if (i >= E) return;
  int is64 = flags[1];
  int s = edge_idx(ei, i, is64);
  int d = edge_idx(ei, (long)E + i, is64);
  if ((unsigned)s >= (unsigned)Nn) s = 0;
  if ((unsigned)d >= (unsigned)Nn) d = 0;
  int pos = atomicAdd(&fill[d], 1);
  csr_src[pos] = s;
}

// ==== fused attention, k/v gathered as bf16.
// 1 wave/node; 4 edge-slots x 16 lanes; lane j: dims 8j..8j+7 (head j>>2). ====
__global__ __launch_bounds__(256) void k_edge(
    const float* __restrict__ q, const unsigned short* __restrict__ kk,
    const unsigned short* __restrict__ v, const int* __restrict__ rowptr,
    const int* __restrict__ deg, const int* __restrict__ csr_src,
    const float* __restrict__ p_rel, float* __restrict__ agg, int N) {
  int n = (blockIdx.x * 256 + threadIdx.x) >> 6;
  if (n >= N) return;
  const int lane = threadIdx.x & 63;
  const int g = lane >> 4;
  const int j = lane & 15;
  const int start = rowptr[n];
  const int end = start + deg[n];
  const float prl = p_rel[j >> 2] * 0.17677669529663687f;  // 1/sqrt(32)
  const float4 qa = *(const float4*)(q + (size_t)n * CD + 8 * j);
  const float4 qb = *(const float4*)(q + (size_t)n * CD + 8 * j + 4);
  float m = -INFINITY, den = 0.f;
  float acc[8] = {0.f, 0.f, 0.f, 0.f, 0.f, 0.f, 0.f, 0.f};
  for (int e = start + g; e < end; e += 4) {
    int s = csr_src[e];
    uint4 ku = *(const uint4*)(kk + (size_t)s * CD + 8 * j);  // 8 bf16 = 16 B
    uint4 vu = *(const uint4*)(v + (size_t)s * CD + 8 * j);
    float k0 = bfbits2f(ku.x & 0xffffu), k1 = bfbits2f(ku.x >> 16);
    float k2 = bfbits2f(ku.y & 0xffffu), k3 = bfbits2f(ku.y >> 16);
    float k4 = bfbits2f(ku.z & 0xffffu), k5 = bfbits2f(ku.z >> 16);
    float k6 = bfbits2f(ku.w & 0xffffu), k7 = bfbits2f(ku.w >> 16);
    float v0 = bfbits2f(vu.x & 0xffffu), v1 = bfbits2f(vu.x >> 16);
    float v2 = bfbits2f(vu.y & 0xffffu), v3 = bfbits2f(vu.y >> 16);
    float v4 = bfbits2f(vu.z & 0xffffu), v5 = bfbits2f(vu.z >> 16);
    float v6 = bfbits2f(vu.w & 0xffffu), v7 = bfbits2f(vu.w >> 16);
    float pd = qa.x * k0 + qa.y * k1 + qa.z * k2 + qa.w * k3 +
               qb.x * k4 + qb.y * k5 + qb.z * k6 + qb.w * k7;
    pd += __shfl_xor(pd, 1);
    pd += __shfl_xor(pd, 2);
    float a = pd * prl;
    float mn = fmaxf(m, a);
    float sc = __expf(m - mn);
    float ew = __expf(a - mn);
    acc[0] = acc[0] * sc + ew * v0; acc[1] = acc[1] * sc + ew * v1;
    acc[2] = acc[2] * sc + ew * v2; acc[3] = acc[3] * sc + ew * v3;
    acc[4] = acc[4] * sc + ew * v4; acc[5] = acc[5] * sc + ew * v5;
    acc[6] = acc[6] * sc + ew * v6; acc[7] = acc[7] * sc + ew * v7;
    den = den * sc + ew;
    m = mn;
  }
#pragma unroll
  for (int off = 16; off <= 32; off <<= 1) {
    float mo = __shfl_xor(m, off);
    float dno = __shfl_xor(den, off);
    float ao[8];
#pragma unroll
    for (int i = 0; i < 8; i++) ao[i] = __shfl_xor(acc[i], off);
    float mn = fmaxf(m, mo);
    float s1 = (den > 0.f) ? __expf(m - mn) : 0.f;
    float s2 = (dno > 0.f) ? __expf(mo - mn) : 0.f;
#pragma unroll
    for (int i = 0; i < 8; i++) acc[i] = acc[i] * s1 + ao[i] * s2;
    den = den * s1 + dno * s2;
    m = mn;
  }
  if (g == 0) {
    float inv = (den > 0.f) ? 1.f / den : 0.f;
    float4 o0 = make_float4(acc[0] * inv, acc[1] * inv, acc[2] * inv, acc[3] * inv);
    float4 o1 = make_float4(acc[4] * inv, acc[5] * inv, acc[6] * inv, acc[7] * inv);
    *(float4*)(agg + (size_t)n * CD + 8 * j) = o0;
    *(float4*)(agg + (size_t)n * CD + 8 * j + 4) = o1;
  }
}

// ---- out[n,0:2] = h[n,:] @ Wfc + bfc; f32 out if flags[0] else bf16 ----
__global__ __launch_bounds__(256) void k_final(const float* __restrict__ h,
                                               const float* __restrict__ Wfc,
                                               const float* __restrict__ bfc,
                                               void* __restrict__ out,
                                               const int* __restrict__ flags, int N) {
  int g = (blockIdx.x * 256 + threadIdx.x) >> 5;
  int lane = threadIdx.x & 31;
  if (g >= N) return;
  const float* hr = h + (size_t)g * CD;
  float a0 = 0.f, a1 = 0.f;
#pragma unroll
  for (int j = 0; j < 4; j++) {
    float hv = hr[lane + 32 * j];
    a0 += hv * Wfc[(lane + 32 * j) * 2];
    a1 += hv * Wfc[(lane + 32 * j) * 2 + 1];
  }
#pragma unroll
  for (int off = 16; off; off >>= 1) {
    a0 += __shfl_xor(a0, off);
    a1 += __shfl_xor(a1, off);
  }
  if (lane == 0) {
    float o0 = a0 + bfc[0];
    float o1 = a1 + bfc[1];
    if (flags[0]) {
      ((float*)out)[(size_t)g * 2] = o0;
      ((float*)out)[(size_t)g * 2 + 1] = o1;
    } else {
      ((bf16*)out)[(size_t)g * 2] = __float2bfloat16(o0);
      ((bf16*)out)[(size_t)g * 2 + 1] = __float2bfloat16(o1);
    }
  }
}

extern "C" void kernel_launch(void* const* d_in, const int* in_sizes, int n_in,
                              void* d_out, int out_size, void* d_ws, size_t ws_size,
                              hipStream_t stream) {
  const int* ei = (const int*)d_in[1];
  const int N = in_sizes[0] / CD;
  const int E = in_sizes[1] / 2;
  const size_t NC = (size_t)N * CD;
  const int nB = (N + 255) / 256;

  float* p = (float*)d_ws;
  float* hbuf = p;
  float* qbuf = p + NC;                 // q, reused as agg (f32)
  float* kbuf = p + 2 * NC;             // bf16 k lives in first half
  float* vbuf = p + 3 * NC;             // bf16 v lives in first half
  int* ip = (int*)(p + 4 * NC);
  int* deg = ip;
  int* tmp = ip + N;
  int* rowptr = ip + 2 * N;
  int* fill = ip + 3 * N;
  int* bsum = ip + 4 * N;
  int* csr_src = ip + 4 * N + nB;
  float* cur = (float*)(csr_src + E);
  float* wkeff = cur; cur += (size_t)LL * CD * CD;
  float* bkeff = cur; cur += (size_t)LL * CD;
  float* wveff = cur; cur += (size_t)LL * CD * CD;
  float* bveff = cur; cur += (size_t)LL * CD;
  float* pblock = cur;
  float* pWk = cur; cur += (size_t)LL * CD * CD;
  float* pbk = cur; cur += (size_t)LL * CD;
  float* pWq = cur; cur += (size_t)LL * CD * CD;
  float* pbq = cur; cur += (size_t)LL * CD;
  float* pWv = cur; cur += (size_t)LL * CD * CD;
  float* pbv = cur; cur += (size_t)LL * CD;
  float* par = cur; cur += (size_t)LL * HH * DH * DH;
  float* pmr = cur; cur += (size_t)LL * HH * DH * DH;
  float* ppr = cur; cur += (size_t)LL * HH;
  float* pWa = cur; cur += (size_t)LL * CD * CD;
  float* pba = cur; cur += (size_t)LL * CD;
  float* pskip = cur; cur += LL;
  float* pWfc = cur; cur += (size_t)CD * 2;
  float* pbfc = cur; cur += 2;
  int* flags = (int*)cur;

  k_detect<<<1, 128, 0, stream>>>(d_in[0], ei, flags);
  k_cvt<<<((int)NC + 255) / 256, 256, 0, stream>>>(d_in[0], hbuf, (int)NC, flags);

  SegTab tab;
  const int sizes[NSEG] = {LL * CD * CD, LL * CD, LL * CD * CD, LL * CD,
                           LL * CD * CD, LL * CD, LL * HH * DH * DH,
                           LL * HH * DH * DH, LL * HH, LL * CD * CD, LL * CD,
                           LL, CD * 2, 2};
  const int srcIdx[NSEG] = {2, 3, 4, 5, 6, 7, 8, 9, 10, 11, 12, 13, 14, 15};
  int off = 0;
  for (int k = 0; k < NSEG; k++) {
    tab.src[k] = d_in[srcIdx[k]];
    tab.off[k] = off;
    off += sizes[k];
  }
  tab.total = off;
  k_cvt_params<<<(off + 255) / 256, 256, 0, stream>>>(tab, pblock, flags);

  k_eff<<<dim3(CD + 1, HH, LL * 2), DH, 0, stream>>>(pWk, pbk, pWv, pbv, par, pmr,
                                                     wkeff, bkeff, wveff, bveff);

  hipMemsetAsync(deg, 0, (size_t)N * sizeof(int), stream);
  k_hist<<<(E + 255) / 256, 256, 0, stream>>>(ei, deg, flags, E, N);
  k_scan1<<<nB, 256, 0, stream>>>(deg, tmp, bsum, N);
  k_scan2<<<1, 256, 0, stream>>>(bsum, nB);
  k_scan3<<<nB, 256, 0, stream>>>(tmp, deg, bsum, rowptr, fill, N);
  k_scatter<<<(E + 255) / 256, 256, 0, stream>>>(ei, fill, csr_src, flags, E, N);

  const int gemmBlocks = (N + 127) / 128;
  for (int l = 0; l < LL; l++) {
    k_gemm<false, false, false><<<gemmBlocks, 256, 0, stream>>>(
        hbuf, pWq + (size_t)l * CD * CD, pbq + (size_t)l * CD, qbuf, nullptr, N);
    k_gemm<false, false, true><<<gemmBlocks, 256, 0, stream>>>(
        hbuf, wkeff + (size_t)l * CD * CD, bkeff + (size_t)l * CD, kbuf, nullptr, N);
    k_gemm<false, false, true><<<gemmBlocks, 256, 0, stream>>>(
        hbuf, wveff + (size_t)l * CD * CD, bveff + (size_t)l * CD, vbuf, nullptr, N);

    k_edge<<<(N + 3) / 4, 256, 0, stream>>>(
        qbuf, (const unsigned short*)kbuf, (const unsigned short*)vbuf, rowptr,
        deg, csr_src, ppr + (size_t)l * HH, qbuf, N);

    k_gemm<true, true, false><<<gemmBlocks, 256, 0, stream>>>(
        qbuf, pWa + (size_t)l * CD * CD, pba + (size_t)l * CD, hbuf, pskip + l, N);
  }
  k_final<<<(N + 7) / 8, 256, 0, stream>>>(hbuf, pWfc, pbfc, d_out, flags, N);
}

// Round 11
// 893.416 us; speedup vs baseline: 29.3763x; 1.2706x over previous
//
#include <hip/hip_runtime.h>
#include <hip/hip_bf16.h>
#include <math.h>

#define CD 128
#define HH 4
#define DH 32
#define LL 2

using bf16 = __hip_bfloat16;
using bf16x8 = __attribute__((ext_vector_type(8))) short;  // 8 bf16 (4 VGPRs)
using f32x4 = __attribute__((ext_vector_type(4))) float;

__device__ __forceinline__ float bfbits2f(unsigned int s) {
  return __uint_as_float(s << 16);
}

__device__ __forceinline__ unsigned short f2bfbits(float f) {
  unsigned int u = __float_as_uint(f);
  unsigned int r = (u + 0x7fff + ((u >> 16) & 1)) >> 16;  // RNE
  return (unsigned short)r;
}

__device__ __forceinline__ float gelu_f(float x) {
  return 0.5f * x * (1.0f + erff(x * 0.70710678118654752f));
}

// ---- detect input formats: flags[0]=floats-are-f32, flags[1]=edge-index-is-i64 ----
__global__ void k_detect(const void* __restrict__ x, const int* __restrict__ ei,
                         int* __restrict__ flags) {
  __shared__ int cnt_f32, cnt_i32;
  if (threadIdx.x == 0) { cnt_f32 = 0; cnt_i32 = 0; }
  __syncthreads();
  int t = threadIdx.x;  // 128 threads
  unsigned short u = ((const unsigned short*)x)[2 * t];
  float v = bfbits2f((unsigned int)u);
  float av = fabsf(v);
  if (av != 0.f && (av > 1e8f || av < 1e-8f)) atomicAdd(&cnt_f32, 1);
  if (t < 64) {
    if (((const int*)ei)[2 * t + 1] != 0) atomicAdd(&cnt_i32, 1);
  }
  __syncthreads();
  if (threadIdx.x == 0) {
    flags[0] = (cnt_f32 > 8) ? 1 : 0;
    flags[1] = (cnt_i32 == 0) ? 1 : 0;
  }
}

// ---- x -> f32 hbuf AND bf16 hbuf16 ----
__global__ void k_cvt_x(const void* __restrict__ in, float* __restrict__ out,
                        unsigned short* __restrict__ out16, int n,
                        const int* __restrict__ flags) {
  int i = blockIdx.x * blockDim.x + threadIdx.x;
  if (i >= n) return;
  float v = flags[0] ? ((const float*)in)[i]
                     : bfbits2f((unsigned int)((const unsigned short*)in)[i]);
  out[i] = v;
  out16[i] = f2bfbits(v);
}

// ---- all parameter tensors -> contiguous f32 block, one launch ----
#define NSEG 14
struct SegTab {
  const void* src[NSEG];
  int off[NSEG];
  int total;
};
__global__ void k_cvt_params(SegTab tab, float* __restrict__ dst,
                             const int* __restrict__ flags) {
  int i = blockIdx.x * 256 + threadIdx.x;
  if (i >= tab.total) return;
  int seg = 0;
#pragma unroll
  for (int k = 1; k < NSEG; k++)
    if (i >= tab.off[k]) seg = k;
  int j = i - tab.off[seg];
  const void* src = tab.src[seg];
  dst[i] = flags[0] ? ((const float*)src)[j]
                    : bfbits2f((unsigned int)((const unsigned short*)src)[j]);
}

__device__ __forceinline__ int edge_idx(const int* __restrict__ ei, long pos, int is64) {
  return is64 ? ei[2 * pos] : ei[pos];
}

// ---- fold relation transforms into K/V weights: emit bf16 TRANSPOSED WT[n][k] ----
__global__ void k_eff(const float* __restrict__ Wk, const float* __restrict__ bk,
                      const float* __restrict__ Wv, const float* __restrict__ bv,
                      const float* __restrict__ ar, const float* __restrict__ mr,
                      unsigned short* __restrict__ wkeT, float* __restrict__ bke,
                      unsigned short* __restrict__ wveT, float* __restrict__ bve) {
  int c = blockIdx.x, h = blockIdx.y, z = blockIdx.z;
  int l = z >> 1, which = z & 1;
  int e = threadIdx.x;
  const float* W = (which ? Wv : Wk) + (size_t)l * CD * CD;
  const float* B = (which ? bv : bk) + (size_t)l * CD;
  const float* R = (which ? mr : ar) + (size_t)l * HH * DH * DH + h * DH * DH;
  unsigned short* WoT = (which ? wveT : wkeT) + (size_t)l * CD * CD;
  float* Bo = (which ? bve : bke) + (size_t)l * CD;
  float acc = 0.f;
  if (c < CD) {
#pragma unroll
    for (int d = 0; d < DH; d++) acc += W[c * CD + h * DH + d] * R[d * DH + e];
    WoT[(size_t)(h * DH + e) * CD + c] = f2bfbits(acc);  // transposed [n][k]
  } else {
#pragma unroll
    for (int d = 0; d < DH; d++) acc += B[h * DH + d] * R[d * DH + e];
    Bo[h * DH + e] = acc;
  }
}

// ---- transpose Wq/Wa to bf16 WT[n][k], both layers ----
__global__ void k_wt(const float* __restrict__ Wq, const float* __restrict__ Wa,
                     unsigned short* __restrict__ WqT, unsigned short* __restrict__ WaT) {
  int cout = blockIdx.x, z = blockIdx.y;
  int l = z >> 1, which = z & 1;
  int cin = threadIdx.x;
  const float* W = (which ? Wa : Wq) + (size_t)l * CD * CD;
  unsigned short* WT = (which ? WaT : WqT) + (size_t)l * CD * CD;
  WT[(size_t)cout * CD + cin] = f2bfbits(W[(size_t)cin * CD + cout]);
}

// ==== MFMA GEMM, zero-LDS: y[N,128] = A[N,128](bf16) @ W + b.
// A-frag A[m=lane&15][k=quad*8+j] direct from row-major bf16 A;
// B-frag B[k=quad*8+j][n=lane&15] direct from bf16 WT[n][k].
// C/D: col=lane&15, row=quad*4+reg (m89/m91-verified).
// OUT_MODE: 0 = f32; 1 = bf16; 2 = gated residual -> h(f32) + h16(bf16). ====
template <int OUT_MODE>
__global__ __launch_bounds__(256) void k_gemm_mfma(
    const unsigned short* __restrict__ A, const unsigned short* __restrict__ BT,
    const float* __restrict__ bias, void* __restrict__ y,
    float* __restrict__ h, unsigned short* __restrict__ h16,
    const float* __restrict__ skip, int nrows) {
  const int w = threadIdx.x >> 6;
  const int l = threadIdx.x & 63;
  const int r0 = blockIdx.x * 64 + w * 16;
  if (r0 >= nrows) return;
  const int lrow = l & 15;
  const int quad = l >> 4;
  const int k0 = quad * 8;

  f32x4 acc[8];
#pragma unroll
  for (int ct = 0; ct < 8; ct++) {
    float b = bias[ct * 16 + lrow];
    acc[ct] = (f32x4){b, b, b, b};
  }
  int ar = r0 + lrow;
  if (ar >= nrows) ar = nrows - 1;  // clamp; masked on store
  const unsigned short* Ap = A + (size_t)ar * CD;
#pragma unroll
  for (int kc = 0; kc < 4; kc++) {
    bf16x8 af = *(const bf16x8*)(Ap + kc * 32 + k0);
#pragma unroll
    for (int ct = 0; ct < 8; ct++) {
      bf16x8 bfr = *(const bf16x8*)(BT + (size_t)(ct * 16 + lrow) * CD + kc * 32 + k0);
      acc[ct] = __builtin_amdgcn_mfma_f32_16x16x32_bf16(af, bfr, acc[ct], 0, 0, 0);
    }
  }
  float gg = 0.f;
  if (OUT_MODE == 2) gg = 1.f / (1.f + __expf(-skip[0]));
#pragma unroll
  for (int ct = 0; ct < 8; ct++) {
#pragma unroll
    for (int i = 0; i < 4; i++) {
      int gr = r0 + quad * 4 + i;
      if (gr >= nrows) continue;
      int col = ct * 16 + lrow;
      float val = acc[ct][i];
      if (OUT_MODE == 0) {
        ((float*)y)[(size_t)gr * CD + col] = val;
      } else if (OUT_MODE == 1) {
        ((unsigned short*)y)[(size_t)gr * CD + col] = f2bfbits(val);
      } else {
        size_t ix = (size_t)gr * CD + col;
        float o = gg * val + (1.f - gg) * h[ix];
        h[ix] = o;
        h16[ix] = f2bfbits(o);
      }
    }
  }
}

// ==== CSR build ====
__global__ void k_hist(const int* __restrict__ ei, int* __restrict__ deg,
                       const int* __restrict__ flags, int E, int Nn) {
  int i = blockIdx.x * blockDim.x + threadIdx.x;
  if (i >= E) return;
  int d = edge_idx(ei, (long)E + i, flags[1]);
  if ((unsigned)d >= (unsigned)Nn) d = 0;
  atomicAdd(&deg[d], 1);
}

__global__ void k_scan1(const int* __restrict__ deg, int* __restrict__ tmp,
                        int* __restrict__ bsum, int n) {
  __shared__ int sh[256];
  int i = blockIdx.x * 256 + threadIdx.x;
  int v = (i < n) ? deg[i] : 0;
  sh[threadIdx.x] = v;
  __syncthreads();
  for (int off = 1; off < 256; off <<= 1) {
    int t = (threadIdx.x >= off) ? sh[threadIdx.x - off] : 0;
    __syncthreads();
    sh[threadIdx.x] += t;
    __syncthreads();
  }
  if (i < n) tmp[i] = sh[threadIdx.x];
  if (threadIdx.x == 255) bsum[blockIdx.x] = sh[255];
}

__global__ void k_scan2(int* __restrict__ bsum, int nb) {
  __shared__ int sh[256];
  __shared__ int carry;
  if (threadIdx.x == 0) carry = 0;
  __syncthreads();
  for (int base = 0; base < nb; base += 256) {
    int i = base + threadIdx.x;
    int v = (i < nb) ? bsum[i] : 0;
    sh[threadIdx.x] = v;
    __syncthreads();
    for (int off = 1; off < 256; off <<= 1) {
      int t = (threadIdx.x >= off) ? sh[threadIdx.x - off] : 0;
      __syncthreads();
      sh[threadIdx.x] += t;
      __syncthreads();
    }
    if (i < nb) bsum[i] = sh[threadIdx.x] + carry;
    __syncthreads();
    if (threadIdx.x == 0) carry += sh[255];
    __syncthreads();
  }
}

__global__ void k_scan3(const int* __restrict__ tmp, const int* __restrict__ deg,
                        const int* __restrict__ bsum, int* __restrict__ rowptr,
                        int* __restrict__ fill, int n) {
  int i = blockIdx.x * 256 + threadIdx.x;
  if (i >= n) return;
  int off = (blockIdx.x > 0) ? bsum[blockIdx.x - 1] : 0;
  int excl = tmp[i] - deg[i] + off;
  rowptr[i] = excl;
  fill[i] = excl;
}

__global__ void k_scatter(const int* __restrict__ ei, int* __restrict__ fill,
                          int* __restrict__ csr_src, const int* __restrict__ flags,
                          int E, int Nn) {
  int i = blockIdx.x * blockDim.x + threadIdx.x;
  if (i >= E) return;
  int is64 = flags[1];
  int s = edge_idx(ei, i, is64);
  int d = edge_idx(ei, (long)E + i, is64);
  if ((unsigned)s >= (unsigned)Nn) s = 0;
  if ((unsigned)d >= (unsigned)Nn) d = 0;
  int pos = atomicAdd(&fill[d], 1);
  csr_src[pos] = s;
}

// ==== fused attention, k/v bf16; epilogue applies GELU and packs bf16 agg16.
// 1 wave/node; 4 edge-slots x 16 lanes; lane j: dims 8j..8j+7 (head j>>2). ====
__global__ __launch_bounds__(256) void k_edge(
    const float* __restrict__ q, const unsigned short* __restrict__ kk,
    const unsigned short* __restrict__ v, const int* __restrict__ rowptr,
    const int* __restrict__ deg, const int* __restrict__ csr_src,
    const float* __restrict__ p_rel, unsigned short* __restrict__ agg16, int N) {
  int n = (blockIdx.x * 256 + threadIdx.x) >> 6;
  if (n >= N) return;
  const int lane = threadIdx.x & 63;
  const int g = lane >> 4;
  const int j = lane & 15;
  const int start = rowptr[n];
  const int end = start + deg[n];
  const float prl = p_rel[j >> 2] * 0.17677669529663687f;  // 1/sqrt(32)
  const float4 qa = *(const float4*)(q + (size_t)n * CD + 8 * j);
  const float4 qb = *(const float4*)(q + (size_t)n * CD + 8 * j + 4);
  float m = -INFINITY, den = 0.f;
  float acc[8] = {0.f, 0.f, 0.f, 0.f, 0.f, 0.f, 0.f, 0.f};
  for (int e = start + g; e < end; e += 4) {
    int s = csr_src[e];
    uint4 ku = *(const uint4*)(kk + (size_t)s * CD + 8 * j);  // 8 bf16 = 16 B
    uint4 vu = *(const uint4*)(v + (size_t)s * CD + 8 * j);
    float k0 = bfbits2f(ku.x & 0xffffu), k1 = bfbits2f(ku.x >> 16);
    float k2 = bfbits2f(ku.y & 0xffffu), k3 = bfbits2f(ku.y >> 16);
    float k4 = bfbits2f(ku.z & 0xffffu), k5 = bfbits2f(ku.z >> 16);
    float k6 = bfbits2f(ku.w & 0xffffu), k7 = bfbits2f(ku.w >> 16);
    float v0 = bfbits2f(vu.x & 0xffffu), v1 = bfbits2f(vu.x >> 16);
    float v2 = bfbits2f(vu.y & 0xffffu), v3 = bfbits2f(vu.y >> 16);
    float v4 = bfbits2f(vu.z & 0xffffu), v5 = bfbits2f(vu.z >> 16);
    float v6 = bfbits2f(vu.w & 0xffffu), v7 = bfbits2f(vu.w >> 16);
    float pd = qa.x * k0 + qa.y * k1 + qa.z * k2 + qa.w * k3 +
               qb.x * k4 + qb.y * k5 + qb.z * k6 + qb.w * k7;
    pd += __shfl_xor(pd, 1);
    pd += __shfl_xor(pd, 2);
    float a = pd * prl;
    float mn = fmaxf(m, a);
    float sc = __expf(m - mn);
    float ew = __expf(a - mn);
    acc[0] = acc[0] * sc + ew * v0; acc[1] = acc[1] * sc + ew * v1;
    acc[2] = acc[2] * sc + ew * v2; acc[3] = acc[3] * sc + ew * v3;
    acc[4] = acc[4] * sc + ew * v4; acc[5] = acc[5] * sc + ew * v5;
    acc[6] = acc[6] * sc + ew * v6; acc[7] = acc[7] * sc + ew * v7;
    den = den * sc + ew;
    m = mn;
  }
#pragma unroll
  for (int off = 16; off <= 32; off <<= 1) {
    float mo = __shfl_xor(m, off);
    float dno = __shfl_xor(den, off);
    float ao[8];
#pragma unroll
    for (int i = 0; i < 8; i++) ao[i] = __shfl_xor(acc[i], off);
    float mn = fmaxf(m, mo);
    float s1 = (den > 0.f) ? __expf(m - mn) : 0.f;
    float s2 = (dno > 0.f) ? __expf(mo - mn) : 0.f;
#pragma unroll
    for (int i = 0; i < 8; i++) acc[i] = acc[i] * s1 + ao[i] * s2;
    den = den * s1 + dno * s2;
    m = mn;
  }
  if (g == 0) {
    float inv = (den > 0.f) ? 1.f / den : 0.f;
    ushort4 o0, o1;
    o0.x = f2bfbits(gelu_f(acc[0] * inv)); o0.y = f2bfbits(gelu_f(acc[1] * inv));
    o0.z = f2bfbits(gelu_f(acc[2] * inv)); o0.w = f2bfbits(gelu_f(acc[3] * inv));
    o1.x = f2bfbits(gelu_f(acc[4] * inv)); o1.y = f2bfbits(gelu_f(acc[5] * inv));
    o1.z = f2bfbits(gelu_f(acc[6] * inv)); o1.w = f2bfbits(gelu_f(acc[7] * inv));
    *(ushort4*)(agg16 + (size_t)n * CD + 8 * j) = o0;
    *(ushort4*)(agg16 + (size_t)n * CD + 8 * j + 4) = o1;
  }
}

// ---- out[n,0:2] = h[n,:] @ Wfc + bfc; f32 out if flags[0] else bf16 ----
__global__ __launch_bounds__(256) void k_final(const float* __restrict__ h,
                                               const float* __restrict__ Wfc,
                                               const float* __restrict__ bfc,
                                               void* __restrict__ out,
                                               const int* __restrict__ flags, int N) {
  int g = (blockIdx.x * 256 + threadIdx.x) >> 5;
  int lane = threadIdx.x & 31;
  if (g >= N) return;
  const float* hr = h + (size_t)g * CD;
  float a0 = 0.f, a1 = 0.f;
#pragma unroll
  for (int j = 0; j < 4; j++) {
    float hv = hr[lane + 32 * j];
    a0 += hv * Wfc[(lane + 32 * j) * 2];
    a1 += hv * Wfc[(lane + 32 * j) * 2 + 1];
  }
#pragma unroll
  for (int off = 16; off; off >>= 1) {
    a0 += __shfl_xor(a0, off);
    a1 += __shfl_xor(a1, off);
  }
  if (lane == 0) {
    float o0 = a0 + bfc[0];
    float o1 = a1 + bfc[1];
    if (flags[0]) {
      ((float*)out)[(size_t)g * 2] = o0;
      ((float*)out)[(size_t)g * 2 + 1] = o1;
    } else {
      ((bf16*)out)[(size_t)g * 2] = __float2bfloat16(o0);
      ((bf16*)out)[(size_t)g * 2 + 1] = __float2bfloat16(o1);
    }
  }
}

extern "C" void kernel_launch(void* const* d_in, const int* in_sizes, int n_in,
                              void* d_out, int out_size, void* d_ws, size_t ws_size,
                              hipStream_t stream) {
  const int* ei = (const int*)d_in[1];
  const int N = in_sizes[0] / CD;
  const int E = in_sizes[1] / 2;
  const size_t NC = (size_t)N * CD;
  const int nB = (N + 255) / 256;

  float* p = (float*)d_ws;
  float* hbuf = p;                                    // NC f32
  float* qbuf = p + NC;                               // NC f32
  float* cur = p + 2 * NC;
  unsigned short* hbuf16 = (unsigned short*)cur; cur += NC / 2;
  unsigned short* kbuf16 = (unsigned short*)cur; cur += NC / 2;
  unsigned short* vbuf16 = (unsigned short*)cur; cur += NC / 2;
  unsigned short* agg16 = (unsigned short*)cur; cur += NC / 2;
  int* ip = (int*)cur;
  int* deg = ip;
  int* tmp = ip + N;
  int* rowptr = ip + 2 * N;
  int* fill = ip + 3 * N;
  int* bsum = ip + 4 * N;
  int* csr_src = ip + 4 * N + nB;
  cur = (float*)(csr_src + E);
  unsigned short* wkeT = (unsigned short*)cur; cur += (size_t)LL * CD * CD / 2;
  unsigned short* wveT = (unsigned short*)cur; cur += (size_t)LL * CD * CD / 2;
  unsigned short* wqT = (unsigned short*)cur; cur += (size_t)LL * CD * CD / 2;
  unsigned short* waT = (unsigned short*)cur; cur += (size_t)LL * CD * CD / 2;
  float* bke = cur; cur += (size_t)LL * CD;
  float* bve = cur; cur += (size_t)LL * CD;
  float* pblock = cur;
  float* pWk = cur; cur += (size_t)LL * CD * CD;
  float* pbk = cur; cur += (size_t)LL * CD;
  float* pWq = cur; cur += (size_t)LL * CD * CD;
  float* pbq = cur; cur += (size_t)LL * CD;
  float* pWv = cur; cur += (size_t)LL * CD * CD;
  float* pbv = cur; cur += (size_t)LL * CD;
  float* par = cur; cur += (size_t)LL * HH * DH * DH;
  float* pmr = cur; cur += (size_t)LL * HH * DH * DH;
  float* ppr = cur; cur += (size_t)LL * HH;
  float* pWa = cur; cur += (size_t)LL * CD * CD;
  float* pba = cur; cur += (size_t)LL * CD;
  float* pskip = cur; cur += LL;
  float* pWfc = cur; cur += (size_t)CD * 2;
  float* pbfc = cur; cur += 2;
  int* flags = (int*)cur;

  k_detect<<<1, 128, 0, stream>>>(d_in[0], ei, flags);
  k_cvt_x<<<((int)NC + 255) / 256, 256, 0, stream>>>(d_in[0], hbuf, hbuf16,
                                                     (int)NC, flags);

  SegTab tab;
  const int sizes[NSEG] = {LL * CD * CD, LL * CD, LL * CD * CD, LL * CD,
                           LL * CD * CD, LL * CD, LL * HH * DH * DH,
                           LL * HH * DH * DH, LL * HH, LL * CD * CD, LL * CD,
                           LL, CD * 2, 2};
  const int srcIdx[NSEG] = {2, 3, 4, 5, 6, 7, 8, 9, 10, 11, 12, 13, 14, 15};
  int off = 0;
  for (int k = 0; k < NSEG; k++) {
    tab.src[k] = d_in[srcIdx[k]];
    tab.off[k] = off;
    off += sizes[k];
  }
  tab.total = off;
  k_cvt_params<<<(off + 255) / 256, 256, 0, stream>>>(tab, pblock, flags);

  k_eff<<<dim3(CD + 1, HH, LL * 2), DH, 0, stream>>>(pWk, pbk, pWv, pbv, par, pmr,
                                                     wkeT, bke, wveT, bve);
  k_wt<<<dim3(CD, 2 * LL), CD, 0, stream>>>(pWq, pWa, wqT, waT);

  hipMemsetAsync(deg, 0, (size_t)N * sizeof(int), stream);
  k_hist<<<(E + 255) / 256, 256, 0, stream>>>(ei, deg, flags, E, N);
  k_scan1<<<nB, 256, 0, stream>>>(deg, tmp, bsum, N);
  k_scan2<<<1, 256, 0, stream>>>(bsum, nB);
  k_scan3<<<nB, 256, 0, stream>>>(tmp, deg, bsum, rowptr, fill, N);
  k_scatter<<<(E + 255) / 256, 256, 0, stream>>>(ei, fill, csr_src, flags, E, N);

  const int mfmaBlocks = (N + 63) / 64;
  for (int l = 0; l < LL; l++) {
    k_gemm_mfma<0><<<mfmaBlocks, 256, 0, stream>>>(
        hbuf16, wqT + (size_t)l * CD * CD, pbq + (size_t)l * CD, qbuf,
        nullptr, nullptr, nullptr, N);
    k_gemm_mfma<1><<<mfmaBlocks, 256, 0, stream>>>(
        hbuf16, wkeT + (size_t)l * CD * CD, bke + (size_t)l * CD, kbuf16,
        nullptr, nullptr, nullptr, N);
    k_gemm_mfma<1><<<mfmaBlocks, 256, 0, stream>>>(
        hbuf16, wveT + (size_t)l * CD * CD, bve + (size_t)l * CD, vbuf16,
        nullptr, nullptr, nullptr, N);

    k_edge<<<(N + 3) / 4, 256, 0, stream>>>(qbuf, kbuf16, vbuf16, rowptr, deg,
                                            csr_src, ppr + (size_t)l * HH, agg16, N);

    // gelu(agg)@Wa + ba, gated residual -> hbuf (f32) + hbuf16 (bf16)
    k_gemm_mfma<2><<<mfmaBlocks, 256, 0, stream>>>(
        agg16, waT + (size_t)l * CD * CD, pba + (size_t)l * CD, nullptr,
        hbuf, hbuf16, pskip + l, N);
  }
  k_final<<<(N + 7) / 8, 256, 0, stream>>>(hbuf, pWfc, pbfc, d_out, flags, N);
}